// Round 4
// baseline (4794.571 us; speedup 1.0000x reference)
//
#include <hip/hip_runtime.h>
#include <math.h>

#define HQn 16
#define HKn 4
#define Gn 4
#define Dn 128
#define STRIDEn 16
#define CBLKn 32
#define SBLKn 64
#define NSELn 16
#define WINn 512
#define Sn 2048
#define Cn 127
#define NBLKn 32

typedef float f32x4 __attribute__((ext_vector_type(4)));
typedef __bf16 bf16x8 __attribute__((ext_vector_type(8)));
typedef unsigned short ushort8 __attribute__((ext_vector_type(8)));
typedef unsigned int uint2v __attribute__((ext_vector_type(2)));

__device__ inline f32x4 mfma16(bf16x8 a, bf16x8 b, f32x4 c) {
  return __builtin_amdgcn_mfma_f32_16x16x32_bf16(a, b, c, 0, 0, 0);
}
__device__ inline unsigned short f2bfu(float x) {
  return __builtin_bit_cast(unsigned short, (__bf16)x);
}
__device__ inline unsigned pk2(float a, float b) {
  return (unsigned)f2bfu(a) | ((unsigned)f2bfu(b) << 16);
}
__device__ inline void gll16(const void* g, void* l) {
  __builtin_amdgcn_global_load_lds(
      (const __attribute__((address_space(1))) unsigned*)g,
      (__attribute__((address_space(3))) unsigned*)l, 16, 0, 0);
}

// ---------------------------------------------------------------------------
// Convert q (pre-scaled) and k to bf16; k relayout [t][hk][d] -> [hk][t][d].
// ---------------------------------------------------------------------------
__global__ __launch_bounds__(256)
void nsa_cvtq(const float* __restrict__ q, const float* __restrict__ k,
              unsigned short* __restrict__ qbf, unsigned short* __restrict__ kbf) {
  const float scale = 0.08838834764831845f;
  const int gid = blockIdx.x * 256 + threadIdx.x;
  if (gid < 524288) {
    const size_t i = (size_t)gid * 8;
    const float4* s = (const float4*)(q + i);
    float4 a = s[0], b = s[1];
    ushort8 u;
    u[0]=f2bfu(a.x*scale); u[1]=f2bfu(a.y*scale); u[2]=f2bfu(a.z*scale); u[3]=f2bfu(a.w*scale);
    u[4]=f2bfu(b.x*scale); u[5]=f2bfu(b.y*scale); u[6]=f2bfu(b.z*scale); u[7]=f2bfu(b.w*scale);
    *(ushort8*)(qbf + i) = u;
  } else {
    const int g2 = gid - 524288;           // < 131072
    const size_t o = (size_t)g2 * 8;
    const int hk = (int)(o >> 18);
    const int r  = (int)(o & 262143);
    const int t = r >> 7, d = r & 127;
    const float4* s = (const float4*)(k + ((size_t)t * 4 + hk) * 128 + d);
    float4 a = s[0], b = s[1];
    ushort8 u;
    u[0]=f2bfu(a.x); u[1]=f2bfu(a.y); u[2]=f2bfu(a.z); u[3]=f2bfu(a.w);
    u[4]=f2bfu(b.x); u[5]=f2bfu(b.y); u[6]=f2bfu(b.z); u[7]=f2bfu(b.w);
    *(ushort8*)(kbf + o) = u;
  }
}

// ---------------------------------------------------------------------------
// V -> bf16 transposed: vtb[hk][d][t]
// ---------------------------------------------------------------------------
__global__ __launch_bounds__(256)
void nsa_cvtv(const float* __restrict__ v, unsigned short* __restrict__ vtb) {
  __shared__ __align__(16) unsigned short tile[64][136];
  const int tid = threadIdx.x;
  const int tb = blockIdx.x * 64, hk = blockIdx.y;
  {
    const int tl = tid >> 2, dc = (tid & 3) * 32;
    const float4* src = (const float4*)(v + ((size_t)(tb + tl) * 4 + hk) * 128 + dc);
#pragma unroll
    for (int ii = 0; ii < 4; ++ii) {
      float4 a = src[ii * 2], b = src[ii * 2 + 1];
      ushort8 u;
      u[0]=f2bfu(a.x); u[1]=f2bfu(a.y); u[2]=f2bfu(a.z); u[3]=f2bfu(a.w);
      u[4]=f2bfu(b.x); u[5]=f2bfu(b.y); u[6]=f2bfu(b.z); u[7]=f2bfu(b.w);
      *(ushort8*)&tile[tl][dc + ii * 8] = u;
    }
  }
  __syncthreads();
  {
    const int d = tid >> 1, th = tid & 1;
    ushort8 u[4];
#pragma unroll
    for (int ii = 0; ii < 4; ++ii)
#pragma unroll
      for (int t = 0; t < 8; ++t)
        u[ii][t] = tile[th * 32 + ii * 8 + t][d];
    ushort8* dst = (ushort8*)(vtb + (size_t)hk * 262144 + (size_t)d * 2048 + tb + th * 32);
#pragma unroll
    for (int ii = 0; ii < 4; ++ii) dst[ii] = u[ii];
  }
}

// ---------------------------------------------------------------------------
// Compression partials (f32, bit-identical expression/order to verified r2).
// ---------------------------------------------------------------------------
__global__ __launch_bounds__(512)
void nsa_compress(const float* __restrict__ k, const float* __restrict__ v,
                  const float* __restrict__ Wk, const float* __restrict__ Wv,
                  float* __restrict__ part) {
  const int wf = blockIdx.z;
  const int which = wf >> 2, fs = wf & 3;
  const int hk = blockIdx.y;
  const int c = blockIdx.x * 16 + (threadIdx.x >> 5);
  const int e0 = (threadIdx.x & 31) * 4;
  if (c >= Cn) return;
  const float* src = which ? v : k;
  const float* W = which ? Wv : Wk;
  float a0 = 0.f, a1 = 0.f, a2 = 0.f, a3 = 0.f;
  const int w0 = fs * 8;
  for (int wi = 0; wi < 8; ++wi) {
    const int row = c * STRIDEn + w0 + wi;
    const float4* kr = (const float4*)(src + ((size_t)row * HKn + hk) * Dn);
    const float* Wr = W + (size_t)(w0 + wi) * Dn * Dn;
#pragma unroll 4
    for (int d4 = 0; d4 < 32; ++d4) {
      float4 kk = kr[d4];
      float4 w0v = *(const float4*)(Wr + (size_t)(d4 * 4 + 0) * Dn + e0);
      float4 w1v = *(const float4*)(Wr + (size_t)(d4 * 4 + 1) * Dn + e0);
      float4 w2v = *(const float4*)(Wr + (size_t)(d4 * 4 + 2) * Dn + e0);
      float4 w3v = *(const float4*)(Wr + (size_t)(d4 * 4 + 3) * Dn + e0);
      a0 += kk.x * w0v.x + kk.y * w1v.x + kk.z * w2v.x + kk.w * w3v.x;
      a1 += kk.x * w0v.y + kk.y * w1v.y + kk.z * w2v.y + kk.w * w3v.y;
      a2 += kk.x * w0v.z + kk.y * w1v.z + kk.z * w2v.z + kk.w * w3v.z;
      a3 += kk.x * w0v.w + kk.y * w1v.w + kk.z * w2v.w + kk.w * w3v.w;
    }
  }
  float* d = part + (size_t)(which * 4 + fs) * (HKn * Cn * Dn)
                  + ((size_t)hk * Cn + c) * Dn + e0;
  d[0] = a0; d[1] = a1; d[2] = a2; d[3] = a3;
}

__global__ void nsa_reduce(const float* __restrict__ part,
                           float* __restrict__ ck, float* __restrict__ cv) {
  const int i = blockIdx.x * 256 + threadIdx.x;
  const int N = HKn * Cn * Dn;
  if (i < N) {
    ck[i] = ((part[i] + part[(size_t)N + i]) + (part[2 * (size_t)N + i] + part[3 * (size_t)N + i]));
    cv[i] = ((part[4 * (size_t)N + i] + part[5 * (size_t)N + i]) + (part[6 * (size_t)N + i] + part[7 * (size_t)N + i]));
  }
}

// ---------------------------------------------------------------------------
// Compressed attention + selection + gates. Selection math bit-identical r2.
// ---------------------------------------------------------------------------
__global__ __launch_bounds__(256)
void nsa_cmp_sel(const float* __restrict__ q, const float* __restrict__ ck,
                 const float* __restrict__ cv, const float* __restrict__ Wg,
                 const float* __restrict__ bg, float* __restrict__ gates,
                 unsigned long long* __restrict__ selm, float* __restrict__ out) {
  __shared__ float pcs2[4][128][4];
  __shared__ float score_l[4][128];
  __shared__ float gate2_l[4][Gn];
  const int wid = threadIdx.x >> 6, lane = threadIdx.x & 63;
  const int s = blockIdx.x * 4 + wid;
  const int hk = blockIdx.y;
  const float scale = 0.08838834764831845f;
  const int cmax = (s >= CBLKn - 1) ? ((s - (CBLKn - 1)) >> 4) + 1 : 0;

  const float4* qg = (const float4*)(q + ((size_t)s * HQn + hk * Gn) * Dn);
  const int c1l = (lane + 64 < Cn) ? lane + 64 : Cn - 1;
  const float4* k0p = (const float4*)(ck + ((size_t)hk * Cn + lane) * Dn);
  const float4* k1p = (const float4*)(ck + ((size_t)hk * Cn + c1l) * Dn);
  float a00=0,a01=0,a10=0,a11=0,a20=0,a21=0,a30=0,a31=0;
#pragma unroll 8
  for (int d4 = 0; d4 < 32; ++d4) {
    const float4 k0 = k0p[d4], k1 = k1p[d4];
    const float4 q0 = qg[0*32 + d4], q1 = qg[1*32 + d4];
    const float4 q2 = qg[2*32 + d4], q3 = qg[3*32 + d4];
    a00 += k0.x*q0.x + k0.y*q0.y + k0.z*q0.z + k0.w*q0.w;
    a01 += k1.x*q0.x + k1.y*q0.y + k1.z*q0.z + k1.w*q0.w;
    a10 += k0.x*q1.x + k0.y*q1.y + k0.z*q1.z + k0.w*q1.w;
    a11 += k1.x*q1.x + k1.y*q1.y + k1.z*q1.z + k1.w*q1.w;
    a20 += k0.x*q2.x + k0.y*q2.y + k0.z*q2.z + k0.w*q2.w;
    a21 += k1.x*q2.x + k1.y*q2.y + k1.z*q2.z + k1.w*q2.w;
    a30 += k0.x*q3.x + k0.y*q3.y + k0.z*q3.z + k0.w*q3.w;
    a31 += k1.x*q3.x + k1.y*q3.y + k1.z*q3.z + k1.w*q3.w;
  }
  float x0[4] = {a00*scale, a10*scale, a20*scale, a30*scale};
  float x1[4] = {a01*scale, a11*scale, a21*scale, a31*scale};

  float p0[4], p1[4];
#pragma unroll
  for (int g = 0; g < 4; ++g) {
    float m = -1e30f;
    if (lane < cmax) m = x0[g];
    if (lane + 64 < cmax) m = fmaxf(m, x1[g]);
    for (int off = 32; off; off >>= 1) m = fmaxf(m, __shfl_xor(m, off));
    float e0v = (lane < cmax) ? __expf(x0[g] - m) : 0.f;
    float e1v = (lane + 64 < cmax) ? __expf(x1[g] - m) : 0.f;
    float sum = e0v + e1v;
    for (int off = 32; off; off >>= 1) sum += __shfl_xor(sum, off);
    float inv = 1.f / fmaxf(sum, 1e-20f);
    p0[g] = e0v * inv; p1[g] = e1v * inv;
  }
  {
    float4 v0 = {p0[0], p0[1], p0[2], p0[3]};
    float4 v1 = {p1[0], p1[1], p1[2], p1[3]};
    *(float4*)&pcs2[wid][lane][0] = v0;
    *(float4*)&pcs2[wid][lane + 64][0] = v1;
    score_l[wid][lane] = v0.x + v0.y + v0.z + v0.w;
    score_l[wid][lane + 64] = v1.x + v1.y + v1.z + v1.w;
  }
  float pooled; int myj;
  if (lane < NBLKn) {
    myj = lane; float sum = 0.f; int cnt = 0;
    for (int kp = 0; kp <= 4; ++kp) {
      int idx = lane * 4 + kp;
      if (idx < Cn) { sum += score_l[wid][idx]; cnt++; }
    }
    pooled = sum / (float)cnt;
  } else { myj = 63; pooled = -INFINITY; }
  unsigned long long msk = 0ull;
  for (int r = 0; r < NSELn; ++r) {
    float bv = pooled; int bi = myj;
    for (int off = 32; off; off >>= 1) {
      float ov = __shfl_xor(bv, off); int oi = __shfl_xor(bi, off);
      if (ov > bv || (ov == bv && oi < bi)) { bv = ov; bi = oi; }
    }
    msk |= (1ull << bi);
    if (myj == bi) pooled = -INFINITY;
  }
  if (lane == 0) selm[(size_t)s * HKn + hk] = msk;

  if (lane < 48) {
    const int gj = lane >> 2, ch = lane & 3;
    const int g = gj / 3, jj = gj % 3;
    const float* qrow = q + ((size_t)s * HQn + hk * Gn + g) * Dn;
    float a = 0.f;
#pragma unroll 8
    for (int d = ch * 32; d < ch * 32 + 32; ++d) a += qrow[d] * Wg[d * 3 + jj];
    a += __shfl_xor(a, 1); a += __shfl_xor(a, 2);
    if (ch == 0) {
      const float gv = 1.f / (1.f + __expf(-(a + bg[jj])));
      gates[((size_t)s * HQn + hk * Gn + g) * 3 + jj] = gv;
      if (jj == 2) gate2_l[wid][g] = gv;
    }
  }

  {
    float b0[4] = {0,0,0,0}, b1[4] = {0,0,0,0};
    float c0a[4] = {0,0,0,0}, c1a[4] = {0,0,0,0};
    int cc = 0;
    for (; cc + 2 <= cmax; cc += 2) {
      float4 pp = *(const float4*)&pcs2[wid][cc][0];
      float4 qq = *(const float4*)&pcs2[wid][cc + 1][0];
      float va1 = cv[((size_t)hk * Cn + cc) * Dn + lane];
      float va2 = cv[((size_t)hk * Cn + cc) * Dn + lane + 64];
      float vb1 = cv[((size_t)hk * Cn + cc + 1) * Dn + lane];
      float vb2 = cv[((size_t)hk * Cn + cc + 1) * Dn + lane + 64];
      b0[0] += pp.x*va1; b0[1] += pp.y*va1; b0[2] += pp.z*va1; b0[3] += pp.w*va1;
      b1[0] += pp.x*va2; b1[1] += pp.y*va2; b1[2] += pp.z*va2; b1[3] += pp.w*va2;
      c0a[0] += qq.x*vb1; c0a[1] += qq.y*vb1; c0a[2] += qq.z*vb1; c0a[3] += qq.w*vb1;
      c1a[0] += qq.x*vb2; c1a[1] += qq.y*vb2; c1a[2] += qq.z*vb2; c1a[3] += qq.w*vb2;
    }
    if (cc < cmax) {
      float4 pp = *(const float4*)&pcs2[wid][cc][0];
      float va1 = cv[((size_t)hk * Cn + cc) * Dn + lane];
      float va2 = cv[((size_t)hk * Cn + cc) * Dn + lane + 64];
      b0[0] += pp.x*va1; b0[1] += pp.y*va1; b0[2] += pp.z*va1; b0[3] += pp.w*va1;
      b1[0] += pp.x*va2; b1[1] += pp.y*va2; b1[2] += pp.z*va2; b1[3] += pp.w*va2;
    }
#pragma unroll
    for (int g = 0; g < 4; ++g) {
      float g2 = gate2_l[wid][g];
      out[((size_t)s * HQn + hk * Gn + g) * Dn + lane] = g2 * (b0[g] + c0a[g]);
      out[((size_t)s * HQn + hk * Gn + g) * Dn + lane + 64] = g2 * (b1[g] + c1a[g]);
    }
  }
}

// ---------------------------------------------------------------------------
// Stage one 64-token K tile + V^T tile via global_load_lds (linear LDS dest,
// inverse-swizzled global source; read side applies the same XOR).
// ---------------------------------------------------------------------------
__device__ inline void stage_tile(const char* kh, const char* vh, int tb,
                                  char* kb, char* vb, int tid) {
#pragma unroll
  for (int i = 0; i < 4; ++i) {
    const int L = i * 4096 + tid * 16;
    const int row = L >> 8, colb = L & 255;
    gll16(kh + ((size_t)(tb + row) << 8) + (colb ^ ((row & 7) << 4)), kb + L);
  }
#pragma unroll
  for (int i = 0; i < 4; ++i) {
    const int L = i * 4096 + tid * 16;
    const int e = L >> 7, colb = L & 127;
    gll16(vh + ((size_t)e << 12) + ((size_t)tb << 1) + (colb ^ ((e & 7) << 4)), vb + L);
  }
}

// ---------------------------------------------------------------------------
// Single-pass online dual-accumulator attention (sel + win), MFMA bf16.
// Block = 16 s-rows x kv-head; 4 waves = 4 GQA heads. 2-phase dbuf staging.
// Sel-path guards are WAVE-UNIFORM (__any) — per-lane masks only select
// values (zeros contribute nothing); MFMA always runs with full fragments.
// ---------------------------------------------------------------------------
__global__ __launch_bounds__(256, 2)
void nsa_attn(const unsigned short* __restrict__ qbf,
              const unsigned short* __restrict__ kbf,
              const unsigned short* __restrict__ vtb,
              const float* __restrict__ gates,
              const unsigned long long* __restrict__ selm,
              float* __restrict__ out) {
  __shared__ __align__(16) char sK[2][16384];
  __shared__ __align__(16) char sV[2][16384];
  __shared__ __align__(16) char sPa[4][2048];
  __shared__ __align__(16) char sPb[4][2048];

  const int tid = threadIdx.x, lane = tid & 63, w = tid >> 6;
  const int cl = lane & 15, h4 = lane >> 4;
  const int s0 = blockIdx.x * 16, hk = blockIdx.y;
  const int srow = s0 + cl;
  const int head = hk * Gn + w;
  const int swz = (cl & 7) << 4;

  const unsigned long long mymask = selm[(size_t)srow * HKn + hk];
  unsigned long long un = mymask;
  un |= __shfl_xor(un, 1); un |= __shfl_xor(un, 2);
  un |= __shfl_xor(un, 4); un |= __shfl_xor(un, 8);

  const int jmax = (s0 + 15) >> 6;
  const int jw0 = (s0 >= WINn - 1) ? (s0 - (WINn - 1)) >> 6 : 0;
  const unsigned long long allm = (2ull << jmax) - 1;
  unsigned long long nm = (un & allm) | (allm & ~((1ull << jw0) - 1));

  const char* kh = (const char*)kbf + ((size_t)hk << 19);
  const char* vh = (const char*)vtb + ((size_t)hk << 19);

  bf16x8 qb[4];
#pragma unroll
  for (int ks = 0; ks < 4; ++ks)
    qb[ks] = *(const bf16x8*)((const char*)qbf +
        ((size_t)srow * HQn + head) * 256 + ks * 64 + h4 * 16);
  const float g0 = gates[((size_t)srow * HQn + head) * 3 + 0];
  const float g1 = gates[((size_t)srow * HQn + head) * 3 + 1];

  float m = -1e30f, dsel = 0.f, dwin = 0.f;
  f32x4 Oa[8], Ob[8];
#pragma unroll
  for (int ef = 0; ef < 8; ++ef) {
    f32x4 z = {0.f, 0.f, 0.f, 0.f};
    Oa[ef] = z; Ob[ef] = z;
  }

  int j = (int)__builtin_ctzll(nm); nm &= nm - 1;
  stage_tile(kh, vh, j * 64, (char*)sK[0], (char*)sV[0], tid);
  __syncthreads();
  int cur = 0;
  while (true) {
    int jn = -1;
    if (nm) {
      jn = (int)__builtin_ctzll(nm); nm &= nm - 1;
      stage_tile(kh, vh, jn * 64, (char*)sK[cur ^ 1], (char*)sV[cur ^ 1], tid);
    }
    const int tb = j * 64;
    // ---- QK ----
    float xr[16];
#pragma unroll
    for (int mt = 0; mt < 4; ++mt) {
      f32x4 acc = {0.f, 0.f, 0.f, 0.f};
#pragma unroll
      for (int ks = 0; ks < 4; ++ks) {
        const int row = mt * 16 + cl;
        const bf16x8 ka = *(const bf16x8*)(sK[cur] + row * 256 +
            ((unsigned)(ks * 64 + h4 * 16) ^ swz));
        acc = mfma16(ka, qb[ks], acc);
      }
      xr[4*mt+0] = acc[0]; xr[4*mt+1] = acc[1];
      xr[4*mt+2] = acc[2]; xr[4*mt+3] = acc[3];
    }
    // ---- per-lane masks; WAVE-UNIFORM path guards ----
    const bool selb = (mymask >> j) & 1ull;     // per-lane (per q-row)
    const bool anysel = __any(selb);            // wave-uniform
    const bool winb = j >= jw0;                 // wave-uniform
    unsigned va = 0u, vb = 0u;
#pragma unroll
    for (int i = 0; i < 16; ++i) {
      const int token = tb + (i >> 2) * 16 + h4 * 4 + (i & 3);
      const bool cz = token <= srow;
      if (cz && selb) va |= (1u << i);
      if (cz && token >= srow - (WINn - 1)) vb |= (1u << i);
    }
    // ---- online max (defer-max THR=8) ----
    float bm = -1e30f;
    {
      const unsigned vv = va | vb;
#pragma unroll
      for (int i = 0; i < 16; ++i) if ((vv >> i) & 1u) bm = fmaxf(bm, xr[i]);
    }
    bm = fmaxf(bm, __shfl_xor(bm, 16));
    bm = fmaxf(bm, __shfl_xor(bm, 32));
    if (bm > m + 8.f) {
      const float sc = __expf(m - bm);
#pragma unroll
      for (int ef = 0; ef < 8; ++ef) { Oa[ef] *= sc; Ob[ef] *= sc; }
      dsel *= sc; dwin *= sc; m = bm;
    }
    // ---- P = exp(x-m), masked; denominators ----
    float es[16];
#pragma unroll
    for (int i = 0; i < 16; ++i) es[i] = __expf(xr[i] - m);
#pragma unroll
    for (int i = 0; i < 16; ++i) {
      dsel += ((va >> i) & 1u) ? es[i] : 0.f;
      dwin += ((vb >> i) & 1u) ? es[i] : 0.f;
    }
    if (anysel) {   // all lanes write; unselected rows write zeros (va==0)
#pragma unroll
      for (int mt = 0; mt < 4; ++mt) {
        const float p0 = ((va >> (4*mt+0)) & 1u) ? es[4*mt+0] : 0.f;
        const float p1 = ((va >> (4*mt+1)) & 1u) ? es[4*mt+1] : 0.f;
        const float p2 = ((va >> (4*mt+2)) & 1u) ? es[4*mt+2] : 0.f;
        const float p3 = ((va >> (4*mt+3)) & 1u) ? es[4*mt+3] : 0.f;
        uint2v u; u[0] = pk2(p0, p1); u[1] = pk2(p2, p3);
        *(uint2v*)(sPa[w] + cl * 128 + ((unsigned)(mt * 32 + h4 * 8) ^ swz)) = u;
      }
    }
    if (winb) {
#pragma unroll
      for (int mt = 0; mt < 4; ++mt) {
        const float p0 = ((vb >> (4*mt+0)) & 1u) ? es[4*mt+0] : 0.f;
        const float p1 = ((vb >> (4*mt+1)) & 1u) ? es[4*mt+1] : 0.f;
        const float p2 = ((vb >> (4*mt+2)) & 1u) ? es[4*mt+2] : 0.f;
        const float p3 = ((vb >> (4*mt+3)) & 1u) ? es[4*mt+3] : 0.f;
        uint2v u; u[0] = pk2(p0, p1); u[1] = pk2(p2, p3);
        *(uint2v*)(sPb[w] + cl * 128 + ((unsigned)(mt * 32 + h4 * 8) ^ swz)) = u;
      }
    }
    // ---- PV (shared V-frag; guards wave-uniform) ----
#pragma unroll
    for (int kt = 0; kt < 2; ++kt) {
      bf16x8 fa = {}, fb = {};
      if (anysel) fa = *(const bf16x8*)(sPa[w] + cl * 128 +
          ((unsigned)(kt * 64 + h4 * 16) ^ swz));
      if (winb) fb = *(const bf16x8*)(sPb[w] + cl * 128 +
          ((unsigned)(kt * 64 + h4 * 16) ^ swz));
#pragma unroll
      for (int ef = 0; ef < 8; ++ef) {
        const int vrow = ef * 16 + cl;
        const bf16x8 vf = *(const bf16x8*)(sV[cur] + vrow * 128 +
            ((unsigned)(kt * 64 + h4 * 16) ^ swz));
        if (anysel) Oa[ef] = mfma16(vf, fa, Oa[ef]);
        if (winb) Ob[ef] = mfma16(vf, fb, Ob[ef]);
      }
    }
    __syncthreads();
    if (jn < 0) break;
    j = jn; cur ^= 1;
  }

  // ---- epilogue ----
  dsel += __shfl_xor(dsel, 16); dsel += __shfl_xor(dsel, 32);
  dwin += __shfl_xor(dwin, 16); dwin += __shfl_xor(dwin, 32);
  const float ca = g0 / fmaxf(dsel, 1e-20f);
  const float cb = g1 / fmaxf(dwin, 1e-20f);
  float* orow = out + ((size_t)srow * HQn + head) * Dn;
#pragma unroll
  for (int ef = 0; ef < 8; ++ef) {
    float4* p = (float4*)(orow + ef * 16 + h4 * 4);
    float4 o = *p;
    o.x += ca * Oa[ef][0] + cb * Ob[ef][0];
    o.y += ca * Oa[ef][1] + cb * Ob[ef][1];
    o.z += ca * Oa[ef][2] + cb * Ob[ef][2];
    o.w += ca * Oa[ef][3] + cb * Ob[ef][3];
    *p = o;
  }
}

// ---------------------------------------------------------------------------
extern "C" void kernel_launch(void* const* d_in, const int* in_sizes, int n_in,
                              void* d_out, int out_size, void* d_ws, size_t ws_size,
                              hipStream_t stream) {
  const float* q  = (const float*)d_in[0];
  const float* k  = (const float*)d_in[1];
  const float* v  = (const float*)d_in[2];
  const float* Wk = (const float*)d_in[3];
  const float* Wv = (const float*)d_in[4];
  const float* Wg = (const float*)d_in[5];
  const float* bg = (const float*)d_in[6];
  float* out = (float*)d_out;

  const int N = HKn * Cn * Dn;  // 65024
  float* part  = (float*)d_ws;                       // 8*N
  float* ck    = part + (size_t)8 * N;
  float* cv    = ck + N;
  float* gates = cv + N;                             // S*HQ*3 = 98304
  unsigned long long* selm = (unsigned long long*)(gates + (size_t)Sn * HQn * 3); // 8192
  unsigned short* qbf = (unsigned short*)(selm + (size_t)Sn * HKn);  // 4194304
  unsigned short* kbf = qbf + (size_t)Sn * HQn * Dn;                 // 1048576
  unsigned short* vtb = kbf + (size_t)Sn * HKn * Dn;                 // 1048576

  nsa_cvtq<<<2560, 256, 0, stream>>>(q, k, qbf, kbf);
  nsa_cvtv<<<dim3(32, HKn), 256, 0, stream>>>(v, vtb);
  nsa_compress<<<dim3(8, HKn, 8), 512, 0, stream>>>(k, v, Wk, Wv, part);
  nsa_reduce<<<dim3((N + 255) / 256), 256, 0, stream>>>(part, ck, cv);
  nsa_cmp_sel<<<dim3(Sn / 4, HKn), 256, 0, stream>>>(q, ck, cv, Wg, bg, gates, selm, out);
  nsa_attn<<<dim3(Sn / 16, HKn), 256, 0, stream>>>(qbf, kbf, vtb, gates, selm, out);
}

// Round 5
// 2070.604 us; speedup vs baseline: 2.3155x; 2.3155x over previous
//
#include <hip/hip_runtime.h>
#include <math.h>

#define HQn 16
#define HKn 4
#define Gn 4
#define Dn 128
#define STRIDEn 16
#define CBLKn 32
#define SBLKn 64
#define NSELn 16
#define WINn 512
#define Sn 2048
#define Cn 127
#define NBLKn 32

typedef float f32x4 __attribute__((ext_vector_type(4)));
typedef __bf16 bf16x8 __attribute__((ext_vector_type(8)));
typedef unsigned short ushort8 __attribute__((ext_vector_type(8)));
typedef unsigned int uint2v __attribute__((ext_vector_type(2)));

__device__ inline f32x4 mfma16(bf16x8 a, bf16x8 b, f32x4 c) {
  return __builtin_amdgcn_mfma_f32_16x16x32_bf16(a, b, c, 0, 0, 0);
}
__device__ inline unsigned short f2bfu(float x) {
  return __builtin_bit_cast(unsigned short, (__bf16)x);
}
__device__ inline unsigned pk2(float a, float b) {
  return (unsigned)f2bfu(a) | ((unsigned)f2bfu(b) << 16);
}
__device__ inline void gll16(const void* g, void* l) {
  __builtin_amdgcn_global_load_lds(
      (const __attribute__((address_space(1))) unsigned*)g,
      (__attribute__((address_space(3))) unsigned*)l, 16, 0, 0);
}

// ---------------------------------------------------------------------------
// Convert q (pre-scaled) and k to bf16; k relayout [t][hk][d] -> [hk][t][d].
// ---------------------------------------------------------------------------
__global__ __launch_bounds__(256)
void nsa_cvtq(const float* __restrict__ q, const float* __restrict__ k,
              unsigned short* __restrict__ qbf, unsigned short* __restrict__ kbf) {
  const float scale = 0.08838834764831845f;
  const int gid = blockIdx.x * 256 + threadIdx.x;
  if (gid < 524288) {
    const size_t i = (size_t)gid * 8;
    const float4* s = (const float4*)(q + i);
    float4 a = s[0], b = s[1];
    ushort8 u;
    u[0]=f2bfu(a.x*scale); u[1]=f2bfu(a.y*scale); u[2]=f2bfu(a.z*scale); u[3]=f2bfu(a.w*scale);
    u[4]=f2bfu(b.x*scale); u[5]=f2bfu(b.y*scale); u[6]=f2bfu(b.z*scale); u[7]=f2bfu(b.w*scale);
    *(ushort8*)(qbf + i) = u;
  } else {
    const int g2 = gid - 524288;           // < 131072
    const size_t o = (size_t)g2 * 8;
    const int hk = (int)(o >> 18);
    const int r  = (int)(o & 262143);
    const int t = r >> 7, d = r & 127;
    const float4* s = (const float4*)(k + ((size_t)t * 4 + hk) * 128 + d);
    float4 a = s[0], b = s[1];
    ushort8 u;
    u[0]=f2bfu(a.x); u[1]=f2bfu(a.y); u[2]=f2bfu(a.z); u[3]=f2bfu(a.w);
    u[4]=f2bfu(b.x); u[5]=f2bfu(b.y); u[6]=f2bfu(b.z); u[7]=f2bfu(b.w);
    *(ushort8*)(kbf + o) = u;
  }
}

// ---------------------------------------------------------------------------
// V -> bf16 transposed: vtb[hk][d][t]
// ---------------------------------------------------------------------------
__global__ __launch_bounds__(256)
void nsa_cvtv(const float* __restrict__ v, unsigned short* __restrict__ vtb) {
  __shared__ __align__(16) unsigned short tile[64][136];
  const int tid = threadIdx.x;
  const int tb = blockIdx.x * 64, hk = blockIdx.y;
  {
    const int tl = tid >> 2, dc = (tid & 3) * 32;
    const float4* src = (const float4*)(v + ((size_t)(tb + tl) * 4 + hk) * 128 + dc);
#pragma unroll
    for (int ii = 0; ii < 4; ++ii) {
      float4 a = src[ii * 2], b = src[ii * 2 + 1];
      ushort8 u;
      u[0]=f2bfu(a.x); u[1]=f2bfu(a.y); u[2]=f2bfu(a.z); u[3]=f2bfu(a.w);
      u[4]=f2bfu(b.x); u[5]=f2bfu(b.y); u[6]=f2bfu(b.z); u[7]=f2bfu(b.w);
      *(ushort8*)&tile[tl][dc + ii * 8] = u;
    }
  }
  __syncthreads();
  {
    const int d = tid >> 1, th = tid & 1;
    ushort8 u[4];
#pragma unroll
    for (int ii = 0; ii < 4; ++ii)
#pragma unroll
      for (int t = 0; t < 8; ++t)
        u[ii][t] = tile[th * 32 + ii * 8 + t][d];
    ushort8* dst = (ushort8*)(vtb + (size_t)hk * 262144 + (size_t)d * 2048 + tb + th * 32);
#pragma unroll
    for (int ii = 0; ii < 4; ++ii) dst[ii] = u[ii];
  }
}

// ---------------------------------------------------------------------------
// Compression partials (f32, bit-identical expression/order to verified r2).
// ---------------------------------------------------------------------------
__global__ __launch_bounds__(512)
void nsa_compress(const float* __restrict__ k, const float* __restrict__ v,
                  const float* __restrict__ Wk, const float* __restrict__ Wv,
                  float* __restrict__ part) {
  const int wf = blockIdx.z;
  const int which = wf >> 2, fs = wf & 3;
  const int hk = blockIdx.y;
  const int c = blockIdx.x * 16 + (threadIdx.x >> 5);
  const int e0 = (threadIdx.x & 31) * 4;
  if (c >= Cn) return;
  const float* src = which ? v : k;
  const float* W = which ? Wv : Wk;
  float a0 = 0.f, a1 = 0.f, a2 = 0.f, a3 = 0.f;
  const int w0 = fs * 8;
  for (int wi = 0; wi < 8; ++wi) {
    const int row = c * STRIDEn + w0 + wi;
    const float4* kr = (const float4*)(src + ((size_t)row * HKn + hk) * Dn);
    const float* Wr = W + (size_t)(w0 + wi) * Dn * Dn;
#pragma unroll 4
    for (int d4 = 0; d4 < 32; ++d4) {
      float4 kk = kr[d4];
      float4 w0v = *(const float4*)(Wr + (size_t)(d4 * 4 + 0) * Dn + e0);
      float4 w1v = *(const float4*)(Wr + (size_t)(d4 * 4 + 1) * Dn + e0);
      float4 w2v = *(const float4*)(Wr + (size_t)(d4 * 4 + 2) * Dn + e0);
      float4 w3v = *(const float4*)(Wr + (size_t)(d4 * 4 + 3) * Dn + e0);
      a0 += kk.x * w0v.x + kk.y * w1v.x + kk.z * w2v.x + kk.w * w3v.x;
      a1 += kk.x * w0v.y + kk.y * w1v.y + kk.z * w2v.y + kk.w * w3v.y;
      a2 += kk.x * w0v.z + kk.y * w1v.z + kk.z * w2v.z + kk.w * w3v.z;
      a3 += kk.x * w0v.w + kk.y * w1v.w + kk.z * w2v.w + kk.w * w3v.w;
    }
  }
  float* d = part + (size_t)(which * 4 + fs) * (HKn * Cn * Dn)
                  + ((size_t)hk * Cn + c) * Dn + e0;
  d[0] = a0; d[1] = a1; d[2] = a2; d[3] = a3;
}

__global__ void nsa_reduce(const float* __restrict__ part,
                           float* __restrict__ ck, float* __restrict__ cv) {
  const int i = blockIdx.x * 256 + threadIdx.x;
  const int N = HKn * Cn * Dn;
  if (i < N) {
    ck[i] = ((part[i] + part[(size_t)N + i]) + (part[2 * (size_t)N + i] + part[3 * (size_t)N + i]));
    cv[i] = ((part[4 * (size_t)N + i] + part[5 * (size_t)N + i]) + (part[6 * (size_t)N + i] + part[7 * (size_t)N + i]));
  }
}

// ---------------------------------------------------------------------------
// Compressed attention + selection + gates. Selection math bit-identical r2.
// ---------------------------------------------------------------------------
__global__ __launch_bounds__(256)
void nsa_cmp_sel(const float* __restrict__ q, const float* __restrict__ ck,
                 const float* __restrict__ cv, const float* __restrict__ Wg,
                 const float* __restrict__ bg, float* __restrict__ gates,
                 unsigned long long* __restrict__ selm, float* __restrict__ out) {
  __shared__ float pcs2[4][128][4];
  __shared__ float score_l[4][128];
  __shared__ float gate2_l[4][Gn];
  const int wid = threadIdx.x >> 6, lane = threadIdx.x & 63;
  const int s = blockIdx.x * 4 + wid;
  const int hk = blockIdx.y;
  const float scale = 0.08838834764831845f;
  const int cmax = (s >= CBLKn - 1) ? ((s - (CBLKn - 1)) >> 4) + 1 : 0;

  const float4* qg = (const float4*)(q + ((size_t)s * HQn + hk * Gn) * Dn);
  const int c1l = (lane + 64 < Cn) ? lane + 64 : Cn - 1;
  const float4* k0p = (const float4*)(ck + ((size_t)hk * Cn + lane) * Dn);
  const float4* k1p = (const float4*)(ck + ((size_t)hk * Cn + c1l) * Dn);
  float a00=0,a01=0,a10=0,a11=0,a20=0,a21=0,a30=0,a31=0;
#pragma unroll 8
  for (int d4 = 0; d4 < 32; ++d4) {
    const float4 k0 = k0p[d4], k1 = k1p[d4];
    const float4 q0 = qg[0*32 + d4], q1 = qg[1*32 + d4];
    const float4 q2 = qg[2*32 + d4], q3 = qg[3*32 + d4];
    a00 += k0.x*q0.x + k0.y*q0.y + k0.z*q0.z + k0.w*q0.w;
    a01 += k1.x*q0.x + k1.y*q0.y + k1.z*q0.z + k1.w*q0.w;
    a10 += k0.x*q1.x + k0.y*q1.y + k0.z*q1.z + k0.w*q1.w;
    a11 += k1.x*q1.x + k1.y*q1.y + k1.z*q1.z + k1.w*q1.w;
    a20 += k0.x*q2.x + k0.y*q2.y + k0.z*q2.z + k0.w*q2.w;
    a21 += k1.x*q2.x + k1.y*q2.y + k1.z*q2.z + k1.w*q2.w;
    a30 += k0.x*q3.x + k0.y*q3.y + k0.z*q3.z + k0.w*q3.w;
    a31 += k1.x*q3.x + k1.y*q3.y + k1.z*q3.z + k1.w*q3.w;
  }
  float x0[4] = {a00*scale, a10*scale, a20*scale, a30*scale};
  float x1[4] = {a01*scale, a11*scale, a21*scale, a31*scale};

  float p0[4], p1[4];
#pragma unroll
  for (int g = 0; g < 4; ++g) {
    float m = -1e30f;
    if (lane < cmax) m = x0[g];
    if (lane + 64 < cmax) m = fmaxf(m, x1[g]);
    for (int off = 32; off; off >>= 1) m = fmaxf(m, __shfl_xor(m, off));
    float e0v = (lane < cmax) ? __expf(x0[g] - m) : 0.f;
    float e1v = (lane + 64 < cmax) ? __expf(x1[g] - m) : 0.f;
    float sum = e0v + e1v;
    for (int off = 32; off; off >>= 1) sum += __shfl_xor(sum, off);
    float inv = 1.f / fmaxf(sum, 1e-20f);
    p0[g] = e0v * inv; p1[g] = e1v * inv;
  }
  {
    float4 v0 = {p0[0], p0[1], p0[2], p0[3]};
    float4 v1 = {p1[0], p1[1], p1[2], p1[3]};
    *(float4*)&pcs2[wid][lane][0] = v0;
    *(float4*)&pcs2[wid][lane + 64][0] = v1;
    score_l[wid][lane] = v0.x + v0.y + v0.z + v0.w;
    score_l[wid][lane + 64] = v1.x + v1.y + v1.z + v1.w;
  }
  float pooled; int myj;
  if (lane < NBLKn) {
    myj = lane; float sum = 0.f; int cnt = 0;
    for (int kp = 0; kp <= 4; ++kp) {
      int idx = lane * 4 + kp;
      if (idx < Cn) { sum += score_l[wid][idx]; cnt++; }
    }
    pooled = sum / (float)cnt;
  } else { myj = 63; pooled = -INFINITY; }
  unsigned long long msk = 0ull;
  for (int r = 0; r < NSELn; ++r) {
    float bv = pooled; int bi = myj;
    for (int off = 32; off; off >>= 1) {
      float ov = __shfl_xor(bv, off); int oi = __shfl_xor(bi, off);
      if (ov > bv || (ov == bv && oi < bi)) { bv = ov; bi = oi; }
    }
    msk |= (1ull << bi);
    if (myj == bi) pooled = -INFINITY;
  }
  if (lane == 0) selm[(size_t)s * HKn + hk] = msk;

  if (lane < 48) {
    const int gj = lane >> 2, ch = lane & 3;
    const int g = gj / 3, jj = gj % 3;
    const float* qrow = q + ((size_t)s * HQn + hk * Gn + g) * Dn;
    float a = 0.f;
#pragma unroll 8
    for (int d = ch * 32; d < ch * 32 + 32; ++d) a += qrow[d] * Wg[d * 3 + jj];
    a += __shfl_xor(a, 1); a += __shfl_xor(a, 2);
    if (ch == 0) {
      const float gv = 1.f / (1.f + __expf(-(a + bg[jj])));
      gates[((size_t)s * HQn + hk * Gn + g) * 3 + jj] = gv;
      if (jj == 2) gate2_l[wid][g] = gv;
    }
  }

  {
    float b0[4] = {0,0,0,0}, b1[4] = {0,0,0,0};
    float c0a[4] = {0,0,0,0}, c1a[4] = {0,0,0,0};
    int cc = 0;
    for (; cc + 2 <= cmax; cc += 2) {
      float4 pp = *(const float4*)&pcs2[wid][cc][0];
      float4 qq = *(const float4*)&pcs2[wid][cc + 1][0];
      float va1 = cv[((size_t)hk * Cn + cc) * Dn + lane];
      float va2 = cv[((size_t)hk * Cn + cc) * Dn + lane + 64];
      float vb1 = cv[((size_t)hk * Cn + cc + 1) * Dn + lane];
      float vb2 = cv[((size_t)hk * Cn + cc + 1) * Dn + lane + 64];
      b0[0] += pp.x*va1; b0[1] += pp.y*va1; b0[2] += pp.z*va1; b0[3] += pp.w*va1;
      b1[0] += pp.x*va2; b1[1] += pp.y*va2; b1[2] += pp.z*va2; b1[3] += pp.w*va2;
      c0a[0] += qq.x*vb1; c0a[1] += qq.y*vb1; c0a[2] += qq.z*vb1; c0a[3] += qq.w*vb1;
      c1a[0] += qq.x*vb2; c1a[1] += qq.y*vb2; c1a[2] += qq.z*vb2; c1a[3] += qq.w*vb2;
    }
    if (cc < cmax) {
      float4 pp = *(const float4*)&pcs2[wid][cc][0];
      float va1 = cv[((size_t)hk * Cn + cc) * Dn + lane];
      float va2 = cv[((size_t)hk * Cn + cc) * Dn + lane + 64];
      b0[0] += pp.x*va1; b0[1] += pp.y*va1; b0[2] += pp.z*va1; b0[3] += pp.w*va1;
      b1[0] += pp.x*va2; b1[1] += pp.y*va2; b1[2] += pp.z*va2; b1[3] += pp.w*va2;
    }
#pragma unroll
    for (int g = 0; g < 4; ++g) {
      float g2 = gate2_l[wid][g];
      out[((size_t)s * HQn + hk * Gn + g) * Dn + lane] = g2 * (b0[g] + c0a[g]);
      out[((size_t)s * HQn + hk * Gn + g) * Dn + lane + 64] = g2 * (b1[g] + c1a[g]);
    }
  }
}

// ---------------------------------------------------------------------------
// Stage one 64-token K tile + V^T tile via global_load_lds (linear LDS dest,
// inverse-swizzled global source; read side applies the same XOR).
// ---------------------------------------------------------------------------
__device__ inline void stage_tile(const char* kh, const char* vh, int tb,
                                  char* kb, char* vb, int tid) {
#pragma unroll
  for (int i = 0; i < 4; ++i) {
    const int L = i * 4096 + tid * 16;
    const int row = L >> 8, colb = L & 255;
    gll16(kh + ((size_t)(tb + row) << 8) + (colb ^ ((row & 7) << 4)), kb + L);
  }
#pragma unroll
  for (int i = 0; i < 4; ++i) {
    const int L = i * 4096 + tid * 16;
    const int e = L >> 7, colb = L & 127;
    gll16(vh + ((size_t)e << 12) + ((size_t)tb << 1) + (colb ^ ((e & 7) << 4)), vb + L);
  }
}

// ---------------------------------------------------------------------------
// Single-pass online dual-accumulator attention (sel + win), MFMA bf16.
// 1D grid, XCD-swizzled so each XCD serves one kv-head (L2 locality).
// __launch_bounds__(256,1): VGPR cap 512 -> NO SPILL (round-4 regression was
// a 128-VGPR cap spilling Oa/Ob -> 8.5 GB scratch writes per dispatch).
// ---------------------------------------------------------------------------
__global__ __launch_bounds__(256, 1)
void nsa_attn(const unsigned short* __restrict__ qbf,
              const unsigned short* __restrict__ kbf,
              const unsigned short* __restrict__ vtb,
              const float* __restrict__ gates,
              const unsigned long long* __restrict__ selm,
              float* __restrict__ out) {
  __shared__ __align__(16) char sK[2][16384];
  __shared__ __align__(16) char sV[2][16384];
  __shared__ __align__(16) char sPa[4][2048];
  __shared__ __align__(16) char sPb[4][2048];

  const int tid = threadIdx.x, lane = tid & 63, w = tid >> 6;
  const int cl = lane & 15, h4 = lane >> 4;
  // XCD-bijective swizzle: 512 blocks, 8 XCDs, 64 consecutive per XCD.
  const int swzb = (blockIdx.x & 7) * 64 + (blockIdx.x >> 3);
  const int s0 = (swzb & 127) * 16;
  const int hk = swzb >> 7;
  const int srow = s0 + cl;
  const int head = hk * Gn + w;
  const int swz = (cl & 7) << 4;

  const unsigned long long mymask = selm[(size_t)srow * HKn + hk];
  unsigned long long un = mymask;
  un |= __shfl_xor(un, 1); un |= __shfl_xor(un, 2);
  un |= __shfl_xor(un, 4); un |= __shfl_xor(un, 8);

  const int jmax = (s0 + 15) >> 6;
  const int jw0 = (s0 >= WINn - 1) ? (s0 - (WINn - 1)) >> 6 : 0;
  const unsigned long long allm = (2ull << jmax) - 1;
  unsigned long long nm = (un & allm) | (allm & ~((1ull << jw0) - 1));

  const char* kh = (const char*)kbf + ((size_t)hk << 19);
  const char* vh = (const char*)vtb + ((size_t)hk << 19);

  bf16x8 qb[4];
#pragma unroll
  for (int ks = 0; ks < 4; ++ks)
    qb[ks] = *(const bf16x8*)((const char*)qbf +
        ((size_t)srow * HQn + head) * 256 + ks * 64 + h4 * 16);
  const float g0 = gates[((size_t)srow * HQn + head) * 3 + 0];
  const float g1 = gates[((size_t)srow * HQn + head) * 3 + 1];

  float m = -1e30f, dsel = 0.f, dwin = 0.f;
  f32x4 Oa[8], Ob[8];
#pragma unroll
  for (int ef = 0; ef < 8; ++ef) {
    f32x4 z = {0.f, 0.f, 0.f, 0.f};
    Oa[ef] = z; Ob[ef] = z;
  }

  int j = (int)__builtin_ctzll(nm); nm &= nm - 1;
  stage_tile(kh, vh, j * 64, (char*)sK[0], (char*)sV[0], tid);
  __syncthreads();
  int cur = 0;
  while (true) {
    int jn = -1;
    if (nm) {
      jn = (int)__builtin_ctzll(nm); nm &= nm - 1;
      stage_tile(kh, vh, jn * 64, (char*)sK[cur ^ 1], (char*)sV[cur ^ 1], tid);
    }
    const int tb = j * 64;
    // ---- QK ----
    float xr[16];
#pragma unroll
    for (int mt = 0; mt < 4; ++mt) {
      f32x4 acc = {0.f, 0.f, 0.f, 0.f};
#pragma unroll
      for (int ks = 0; ks < 4; ++ks) {
        const int row = mt * 16 + cl;
        const bf16x8 ka = *(const bf16x8*)(sK[cur] + row * 256 +
            ((unsigned)(ks * 64 + h4 * 16) ^ swz));
        acc = mfma16(ka, qb[ks], acc);
      }
      xr[4*mt+0] = acc[0]; xr[4*mt+1] = acc[1];
      xr[4*mt+2] = acc[2]; xr[4*mt+3] = acc[3];
    }
    // ---- per-lane masks; WAVE-UNIFORM path guards ----
    const bool selb = (mymask >> j) & 1ull;     // per-lane (per q-row)
    const bool anysel = __any(selb);            // wave-uniform
    const bool winb = j >= jw0;                 // wave-uniform
    unsigned va = 0u, vb = 0u;
#pragma unroll
    for (int i = 0; i < 16; ++i) {
      const int token = tb + (i >> 2) * 16 + h4 * 4 + (i & 3);
      const bool cz = token <= srow;
      if (cz && selb) va |= (1u << i);
      if (cz && token >= srow - (WINn - 1)) vb |= (1u << i);
    }
    // ---- online max (defer-max THR=8) ----
    float bm = -1e30f;
    {
      const unsigned vv = va | vb;
#pragma unroll
      for (int i = 0; i < 16; ++i) if ((vv >> i) & 1u) bm = fmaxf(bm, xr[i]);
    }
    bm = fmaxf(bm, __shfl_xor(bm, 16));
    bm = fmaxf(bm, __shfl_xor(bm, 32));
    if (bm > m + 8.f) {
      const float sc = __expf(m - bm);
#pragma unroll
      for (int ef = 0; ef < 8; ++ef) { Oa[ef] *= sc; Ob[ef] *= sc; }
      dsel *= sc; dwin *= sc; m = bm;
    }
    // ---- exp in place (xr reused); denominators ----
#pragma unroll
    for (int i = 0; i < 16; ++i) xr[i] = __expf(xr[i] - m);
#pragma unroll
    for (int i = 0; i < 16; ++i) {
      dsel += ((va >> i) & 1u) ? xr[i] : 0.f;
      dwin += ((vb >> i) & 1u) ? xr[i] : 0.f;
    }
    if (anysel) {   // all lanes write; unselected rows write zeros (va==0)
#pragma unroll
      for (int mt = 0; mt < 4; ++mt) {
        const float p0 = ((va >> (4*mt+0)) & 1u) ? xr[4*mt+0] : 0.f;
        const float p1 = ((va >> (4*mt+1)) & 1u) ? xr[4*mt+1] : 0.f;
        const float p2 = ((va >> (4*mt+2)) & 1u) ? xr[4*mt+2] : 0.f;
        const float p3 = ((va >> (4*mt+3)) & 1u) ? xr[4*mt+3] : 0.f;
        uint2v u; u[0] = pk2(p0, p1); u[1] = pk2(p2, p3);
        *(uint2v*)(sPa[w] + cl * 128 + ((unsigned)(mt * 32 + h4 * 8) ^ swz)) = u;
      }
    }
    if (winb) {
#pragma unroll
      for (int mt = 0; mt < 4; ++mt) {
        const float p0 = ((vb >> (4*mt+0)) & 1u) ? xr[4*mt+0] : 0.f;
        const float p1 = ((vb >> (4*mt+1)) & 1u) ? xr[4*mt+1] : 0.f;
        const float p2 = ((vb >> (4*mt+2)) & 1u) ? xr[4*mt+2] : 0.f;
        const float p3 = ((vb >> (4*mt+3)) & 1u) ? xr[4*mt+3] : 0.f;
        uint2v u; u[0] = pk2(p0, p1); u[1] = pk2(p2, p3);
        *(uint2v*)(sPb[w] + cl * 128 + ((unsigned)(mt * 32 + h4 * 8) ^ swz)) = u;
      }
    }
    // ---- PV (shared V-frag; guards wave-uniform) ----
#pragma unroll
    for (int kt = 0; kt < 2; ++kt) {
      bf16x8 fa = {}, fb = {};
      if (anysel) fa = *(const bf16x8*)(sPa[w] + cl * 128 +
          ((unsigned)(kt * 64 + h4 * 16) ^ swz));
      if (winb) fb = *(const bf16x8*)(sPb[w] + cl * 128 +
          ((unsigned)(kt * 64 + h4 * 16) ^ swz));
#pragma unroll
      for (int ef = 0; ef < 8; ++ef) {
        const int vrow = ef * 16 + cl;
        const bf16x8 vf = *(const bf16x8*)(sV[cur] + vrow * 128 +
            ((unsigned)(kt * 64 + h4 * 16) ^ swz));
        if (anysel) Oa[ef] = mfma16(vf, fa, Oa[ef]);
        if (winb) Ob[ef] = mfma16(vf, fb, Ob[ef]);
      }
    }
    __syncthreads();
    if (jn < 0) break;
    j = jn; cur ^= 1;
  }

  // ---- epilogue ----
  dsel += __shfl_xor(dsel, 16); dsel += __shfl_xor(dsel, 32);
  dwin += __shfl_xor(dwin, 16); dwin += __shfl_xor(dwin, 32);
  const float ca = g0 / fmaxf(dsel, 1e-20f);
  const float cb = g1 / fmaxf(dwin, 1e-20f);
  float* orow = out + ((size_t)srow * HQn + head) * Dn;
#pragma unroll
  for (int ef = 0; ef < 8; ++ef) {
    float4* p = (float4*)(orow + ef * 16 + h4 * 4);
    float4 o = *p;
    o.x += ca * Oa[ef][0] + cb * Ob[ef][0];
    o.y += ca * Oa[ef][1] + cb * Ob[ef][1];
    o.z += ca * Oa[ef][2] + cb * Ob[ef][2];
    o.w += ca * Oa[ef][3] + cb * Ob[ef][3];
    *p = o;
  }
}

// ---------------------------------------------------------------------------
extern "C" void kernel_launch(void* const* d_in, const int* in_sizes, int n_in,
                              void* d_out, int out_size, void* d_ws, size_t ws_size,
                              hipStream_t stream) {
  const float* q  = (const float*)d_in[0];
  const float* k  = (const float*)d_in[1];
  const float* v  = (const float*)d_in[2];
  const float* Wk = (const float*)d_in[3];
  const float* Wv = (const float*)d_in[4];
  const float* Wg = (const float*)d_in[5];
  const float* bg = (const float*)d_in[6];
  float* out = (float*)d_out;

  const int N = HKn * Cn * Dn;  // 65024
  float* part  = (float*)d_ws;                       // 8*N
  float* ck    = part + (size_t)8 * N;
  float* cv    = ck + N;
  float* gates = cv + N;                             // S*HQ*3 = 98304
  unsigned long long* selm = (unsigned long long*)(gates + (size_t)Sn * HQn * 3); // 8192
  unsigned short* qbf = (unsigned short*)(selm + (size_t)Sn * HKn);  // 4194304
  unsigned short* kbf = qbf + (size_t)Sn * HQn * Dn;                 // 1048576
  unsigned short* vtb = kbf + (size_t)Sn * HKn * Dn;                 // 1048576

  nsa_cvtq<<<2560, 256, 0, stream>>>(q, k, qbf, kbf);
  nsa_cvtv<<<dim3(32, HKn), 256, 0, stream>>>(v, vtb);
  nsa_compress<<<dim3(8, HKn, 8), 512, 0, stream>>>(k, v, Wk, Wv, part);
  nsa_reduce<<<dim3((N + 255) / 256), 256, 0, stream>>>(part, ck, cv);
  nsa_cmp_sel<<<dim3(Sn / 4, HKn), 256, 0, stream>>>(q, ck, cv, Wg, bg, gates, selm, out);
  nsa_attn<<<512, 256, 0, stream>>>(qbf, kbf, vtb, gates, selm, out);
}

// Round 6
// 394.411 us; speedup vs baseline: 12.1563x; 5.2499x over previous
//
#include <hip/hip_runtime.h>
#include <math.h>

#define HQn 16
#define HKn 4
#define Gn 4
#define Dn 128
#define STRIDEn 16
#define CBLKn 32
#define SBLKn 64
#define NSELn 16
#define WINn 512
#define Sn 2048
#define Cn 127
#define NBLKn 32

typedef float f32x4 __attribute__((ext_vector_type(4)));
typedef __bf16 bf16x8 __attribute__((ext_vector_type(8)));
typedef unsigned short ushort8 __attribute__((ext_vector_type(8)));
typedef unsigned int uint2v __attribute__((ext_vector_type(2)));

__device__ inline f32x4 mfma16(bf16x8 a, bf16x8 b, f32x4 c) {
  return __builtin_amdgcn_mfma_f32_16x16x32_bf16(a, b, c, 0, 0, 0);
}
__device__ inline unsigned short f2bfu(float x) {
  return __builtin_bit_cast(unsigned short, (__bf16)x);
}
__device__ inline unsigned pk2(float a, float b) {
  return (unsigned)f2bfu(a) | ((unsigned)f2bfu(b) << 16);
}
__device__ inline void gll16(const void* g, void* l) {
  __builtin_amdgcn_global_load_lds(
      (const __attribute__((address_space(1))) unsigned*)g,
      (__attribute__((address_space(3))) unsigned*)l, 16, 0, 0);
}

// ---------------------------------------------------------------------------
// Convert q (pre-scaled) and k to bf16; k relayout [t][hk][d] -> [hk][t][d].
// ---------------------------------------------------------------------------
__global__ __launch_bounds__(256)
void nsa_cvtq(const float* __restrict__ q, const float* __restrict__ k,
              unsigned short* __restrict__ qbf, unsigned short* __restrict__ kbf) {
  const float scale = 0.08838834764831845f;
  const int gid = blockIdx.x * 256 + threadIdx.x;
  if (gid < 524288) {
    const size_t i = (size_t)gid * 8;
    const float4* s = (const float4*)(q + i);
    float4 a = s[0], b = s[1];
    ushort8 u;
    u[0]=f2bfu(a.x*scale); u[1]=f2bfu(a.y*scale); u[2]=f2bfu(a.z*scale); u[3]=f2bfu(a.w*scale);
    u[4]=f2bfu(b.x*scale); u[5]=f2bfu(b.y*scale); u[6]=f2bfu(b.z*scale); u[7]=f2bfu(b.w*scale);
    *(ushort8*)(qbf + i) = u;
  } else {
    const int g2 = gid - 524288;           // < 131072
    const size_t o = (size_t)g2 * 8;
    const int hk = (int)(o >> 18);
    const int r  = (int)(o & 262143);
    const int t = r >> 7, d = r & 127;
    const float4* s = (const float4*)(k + ((size_t)t * 4 + hk) * 128 + d);
    float4 a = s[0], b = s[1];
    ushort8 u;
    u[0]=f2bfu(a.x); u[1]=f2bfu(a.y); u[2]=f2bfu(a.z); u[3]=f2bfu(a.w);
    u[4]=f2bfu(b.x); u[5]=f2bfu(b.y); u[6]=f2bfu(b.z); u[7]=f2bfu(b.w);
    *(ushort8*)(kbf + o) = u;
  }
}

// ---------------------------------------------------------------------------
// V -> bf16 transposed: vtb[hk][d][t]
// ---------------------------------------------------------------------------
__global__ __launch_bounds__(256)
void nsa_cvtv(const float* __restrict__ v, unsigned short* __restrict__ vtb) {
  __shared__ __align__(16) unsigned short tile[64][136];
  const int tid = threadIdx.x;
  const int tb = blockIdx.x * 64, hk = blockIdx.y;
  {
    const int tl = tid >> 2, dc = (tid & 3) * 32;
    const float4* src = (const float4*)(v + ((size_t)(tb + tl) * 4 + hk) * 128 + dc);
#pragma unroll
    for (int ii = 0; ii < 4; ++ii) {
      float4 a = src[ii * 2], b = src[ii * 2 + 1];
      ushort8 u;
      u[0]=f2bfu(a.x); u[1]=f2bfu(a.y); u[2]=f2bfu(a.z); u[3]=f2bfu(a.w);
      u[4]=f2bfu(b.x); u[5]=f2bfu(b.y); u[6]=f2bfu(b.z); u[7]=f2bfu(b.w);
      *(ushort8*)&tile[tl][dc + ii * 8] = u;
    }
  }
  __syncthreads();
  {
    const int d = tid >> 1, th = tid & 1;
    ushort8 u[4];
#pragma unroll
    for (int ii = 0; ii < 4; ++ii)
#pragma unroll
      for (int t = 0; t < 8; ++t)
        u[ii][t] = tile[th * 32 + ii * 8 + t][d];
    ushort8* dst = (ushort8*)(vtb + (size_t)hk * 262144 + (size_t)d * 2048 + tb + th * 32);
#pragma unroll
    for (int ii = 0; ii < 4; ++ii) dst[ii] = u[ii];
  }
}

// ---------------------------------------------------------------------------
// Compression partials (f32, bit-identical expression/order to verified r2).
// ---------------------------------------------------------------------------
__global__ __launch_bounds__(512)
void nsa_compress(const float* __restrict__ k, const float* __restrict__ v,
                  const float* __restrict__ Wk, const float* __restrict__ Wv,
                  float* __restrict__ part) {
  const int wf = blockIdx.z;
  const int which = wf >> 2, fs = wf & 3;
  const int hk = blockIdx.y;
  const int c = blockIdx.x * 16 + (threadIdx.x >> 5);
  const int e0 = (threadIdx.x & 31) * 4;
  if (c >= Cn) return;
  const float* src = which ? v : k;
  const float* W = which ? Wv : Wk;
  float a0 = 0.f, a1 = 0.f, a2 = 0.f, a3 = 0.f;
  const int w0 = fs * 8;
  for (int wi = 0; wi < 8; ++wi) {
    const int row = c * STRIDEn + w0 + wi;
    const float4* kr = (const float4*)(src + ((size_t)row * HKn + hk) * Dn);
    const float* Wr = W + (size_t)(w0 + wi) * Dn * Dn;
#pragma unroll 4
    for (int d4 = 0; d4 < 32; ++d4) {
      float4 kk = kr[d4];
      float4 w0v = *(const float4*)(Wr + (size_t)(d4 * 4 + 0) * Dn + e0);
      float4 w1v = *(const float4*)(Wr + (size_t)(d4 * 4 + 1) * Dn + e0);
      float4 w2v = *(const float4*)(Wr + (size_t)(d4 * 4 + 2) * Dn + e0);
      float4 w3v = *(const float4*)(Wr + (size_t)(d4 * 4 + 3) * Dn + e0);
      a0 += kk.x * w0v.x + kk.y * w1v.x + kk.z * w2v.x + kk.w * w3v.x;
      a1 += kk.x * w0v.y + kk.y * w1v.y + kk.z * w2v.y + kk.w * w3v.y;
      a2 += kk.x * w0v.z + kk.y * w1v.z + kk.z * w2v.z + kk.w * w3v.z;
      a3 += kk.x * w0v.w + kk.y * w1v.w + kk.z * w2v.w + kk.w * w3v.w;
    }
  }
  float* d = part + (size_t)(which * 4 + fs) * (HKn * Cn * Dn)
                  + ((size_t)hk * Cn + c) * Dn + e0;
  d[0] = a0; d[1] = a1; d[2] = a2; d[3] = a3;
}

__global__ void nsa_reduce(const float* __restrict__ part,
                           float* __restrict__ ck, float* __restrict__ cv) {
  const int i = blockIdx.x * 256 + threadIdx.x;
  const int N = HKn * Cn * Dn;
  if (i < N) {
    ck[i] = ((part[i] + part[(size_t)N + i]) + (part[2 * (size_t)N + i] + part[3 * (size_t)N + i]));
    cv[i] = ((part[4 * (size_t)N + i] + part[5 * (size_t)N + i]) + (part[6 * (size_t)N + i] + part[7 * (size_t)N + i]));
  }
}

// ---------------------------------------------------------------------------
// Compressed attention + selection + gates. Selection math bit-identical r2.
// ---------------------------------------------------------------------------
__global__ __launch_bounds__(256)
void nsa_cmp_sel(const float* __restrict__ q, const float* __restrict__ ck,
                 const float* __restrict__ cv, const float* __restrict__ Wg,
                 const float* __restrict__ bg, float* __restrict__ gates,
                 unsigned long long* __restrict__ selm, float* __restrict__ out) {
  __shared__ float pcs2[4][128][4];
  __shared__ float score_l[4][128];
  __shared__ float gate2_l[4][Gn];
  const int wid = threadIdx.x >> 6, lane = threadIdx.x & 63;
  const int s = blockIdx.x * 4 + wid;
  const int hk = blockIdx.y;
  const float scale = 0.08838834764831845f;
  const int cmax = (s >= CBLKn - 1) ? ((s - (CBLKn - 1)) >> 4) + 1 : 0;

  const float4* qg = (const float4*)(q + ((size_t)s * HQn + hk * Gn) * Dn);
  const int c1l = (lane + 64 < Cn) ? lane + 64 : Cn - 1;
  const float4* k0p = (const float4*)(ck + ((size_t)hk * Cn + lane) * Dn);
  const float4* k1p = (const float4*)(ck + ((size_t)hk * Cn + c1l) * Dn);
  float a00=0,a01=0,a10=0,a11=0,a20=0,a21=0,a30=0,a31=0;
#pragma unroll 8
  for (int d4 = 0; d4 < 32; ++d4) {
    const float4 k0 = k0p[d4], k1 = k1p[d4];
    const float4 q0 = qg[0*32 + d4], q1 = qg[1*32 + d4];
    const float4 q2 = qg[2*32 + d4], q3 = qg[3*32 + d4];
    a00 += k0.x*q0.x + k0.y*q0.y + k0.z*q0.z + k0.w*q0.w;
    a01 += k1.x*q0.x + k1.y*q0.y + k1.z*q0.z + k1.w*q0.w;
    a10 += k0.x*q1.x + k0.y*q1.y + k0.z*q1.z + k0.w*q1.w;
    a11 += k1.x*q1.x + k1.y*q1.y + k1.z*q1.z + k1.w*q1.w;
    a20 += k0.x*q2.x + k0.y*q2.y + k0.z*q2.z + k0.w*q2.w;
    a21 += k1.x*q2.x + k1.y*q2.y + k1.z*q2.z + k1.w*q2.w;
    a30 += k0.x*q3.x + k0.y*q3.y + k0.z*q3.z + k0.w*q3.w;
    a31 += k1.x*q3.x + k1.y*q3.y + k1.z*q3.z + k1.w*q3.w;
  }
  float x0[4] = {a00*scale, a10*scale, a20*scale, a30*scale};
  float x1[4] = {a01*scale, a11*scale, a21*scale, a31*scale};

  float p0[4], p1[4];
#pragma unroll
  for (int g = 0; g < 4; ++g) {
    float m = -1e30f;
    if (lane < cmax) m = x0[g];
    if (lane + 64 < cmax) m = fmaxf(m, x1[g]);
    for (int off = 32; off; off >>= 1) m = fmaxf(m, __shfl_xor(m, off));
    float e0v = (lane < cmax) ? __expf(x0[g] - m) : 0.f;
    float e1v = (lane + 64 < cmax) ? __expf(x1[g] - m) : 0.f;
    float sum = e0v + e1v;
    for (int off = 32; off; off >>= 1) sum += __shfl_xor(sum, off);
    float inv = 1.f / fmaxf(sum, 1e-20f);
    p0[g] = e0v * inv; p1[g] = e1v * inv;
  }
  {
    float4 v0 = {p0[0], p0[1], p0[2], p0[3]};
    float4 v1 = {p1[0], p1[1], p1[2], p1[3]};
    *(float4*)&pcs2[wid][lane][0] = v0;
    *(float4*)&pcs2[wid][lane + 64][0] = v1;
    score_l[wid][lane] = v0.x + v0.y + v0.z + v0.w;
    score_l[wid][lane + 64] = v1.x + v1.y + v1.z + v1.w;
  }
  float pooled; int myj;
  if (lane < NBLKn) {
    myj = lane; float sum = 0.f; int cnt = 0;
    for (int kp = 0; kp <= 4; ++kp) {
      int idx = lane * 4 + kp;
      if (idx < Cn) { sum += score_l[wid][idx]; cnt++; }
    }
    pooled = sum / (float)cnt;
  } else { myj = 63; pooled = -INFINITY; }
  unsigned long long msk = 0ull;
  for (int r = 0; r < NSELn; ++r) {
    float bv = pooled; int bi = myj;
    for (int off = 32; off; off >>= 1) {
      float ov = __shfl_xor(bv, off); int oi = __shfl_xor(bi, off);
      if (ov > bv || (ov == bv && oi < bi)) { bv = ov; bi = oi; }
    }
    msk |= (1ull << bi);
    if (myj == bi) pooled = -INFINITY;
  }
  if (lane == 0) selm[(size_t)s * HKn + hk] = msk;

  if (lane < 48) {
    const int gj = lane >> 2, ch = lane & 3;
    const int g = gj / 3, jj = gj % 3;
    const float* qrow = q + ((size_t)s * HQn + hk * Gn + g) * Dn;
    float a = 0.f;
#pragma unroll 8
    for (int d = ch * 32; d < ch * 32 + 32; ++d) a += qrow[d] * Wg[d * 3 + jj];
    a += __shfl_xor(a, 1); a += __shfl_xor(a, 2);
    if (ch == 0) {
      const float gv = 1.f / (1.f + __expf(-(a + bg[jj])));
      gates[((size_t)s * HQn + hk * Gn + g) * 3 + jj] = gv;
      if (jj == 2) gate2_l[wid][g] = gv;
    }
  }

  {
    float b0[4] = {0,0,0,0}, b1[4] = {0,0,0,0};
    float c0a[4] = {0,0,0,0}, c1a[4] = {0,0,0,0};
    int cc = 0;
    for (; cc + 2 <= cmax; cc += 2) {
      float4 pp = *(const float4*)&pcs2[wid][cc][0];
      float4 qq = *(const float4*)&pcs2[wid][cc + 1][0];
      float va1 = cv[((size_t)hk * Cn + cc) * Dn + lane];
      float va2 = cv[((size_t)hk * Cn + cc) * Dn + lane + 64];
      float vb1 = cv[((size_t)hk * Cn + cc + 1) * Dn + lane];
      float vb2 = cv[((size_t)hk * Cn + cc + 1) * Dn + lane + 64];
      b0[0] += pp.x*va1; b0[1] += pp.y*va1; b0[2] += pp.z*va1; b0[3] += pp.w*va1;
      b1[0] += pp.x*va2; b1[1] += pp.y*va2; b1[2] += pp.z*va2; b1[3] += pp.w*va2;
      c0a[0] += qq.x*vb1; c0a[1] += qq.y*vb1; c0a[2] += qq.z*vb1; c0a[3] += qq.w*vb1;
      c1a[0] += qq.x*vb2; c1a[1] += qq.y*vb2; c1a[2] += qq.z*vb2; c1a[3] += qq.w*vb2;
    }
    if (cc < cmax) {
      float4 pp = *(const float4*)&pcs2[wid][cc][0];
      float va1 = cv[((size_t)hk * Cn + cc) * Dn + lane];
      float va2 = cv[((size_t)hk * Cn + cc) * Dn + lane + 64];
      b0[0] += pp.x*va1; b0[1] += pp.y*va1; b0[2] += pp.z*va1; b0[3] += pp.w*va1;
      b1[0] += pp.x*va2; b1[1] += pp.y*va2; b1[2] += pp.z*va2; b1[3] += pp.w*va2;
    }
#pragma unroll
    for (int g = 0; g < 4; ++g) {
      float g2 = gate2_l[wid][g];
      out[((size_t)s * HQn + hk * Gn + g) * Dn + lane] = g2 * (b0[g] + c0a[g]);
      out[((size_t)s * HQn + hk * Gn + g) * Dn + lane + 64] = g2 * (b1[g] + c1a[g]);
    }
  }
}

// ---------------------------------------------------------------------------
// Stage one 64-token K tile + V^T tile via global_load_lds (linear LDS dest,
// inverse-swizzled global source; read side applies the same XOR).
// ---------------------------------------------------------------------------
__device__ inline void stage_tile(const char* kh, const char* vh, int tb,
                                  char* kb, char* vb, int tid) {
#pragma unroll
  for (int i = 0; i < 4; ++i) {
    const int L = i * 4096 + tid * 16;
    const int row = L >> 8, colb = L & 255;
    gll16(kh + ((size_t)(tb + row) << 8) + (colb ^ ((row & 7) << 4)), kb + L);
  }
#pragma unroll
  for (int i = 0; i < 4; ++i) {
    const int L = i * 4096 + tid * 16;
    const int e = L >> 7, colb = L & 127;
    gll16(vh + ((size_t)e << 12) + ((size_t)tb << 1) + (colb ^ ((e & 7) << 4)), vb + L);
  }
}

// ---------------------------------------------------------------------------
// Two-phase online-softmax attention (phase 0 = selected, phase 1 = window).
// Single accumulator O[8] per phase; after each phase the scaled result is
// flushed into out and the registers are reused -> peak VGPR ~110, no spill
// (round-4/5 regression: dual accumulators + conditional MFMA selects > 256
// VGPR -> GBs of scratch traffic). All MFMAs unconditional.
// ---------------------------------------------------------------------------
__global__ __launch_bounds__(256, 2)
void nsa_attn(const unsigned short* __restrict__ qbf,
              const unsigned short* __restrict__ kbf,
              const unsigned short* __restrict__ vtb,
              const float* __restrict__ gates,
              const unsigned long long* __restrict__ selm,
              float* __restrict__ out) {
  __shared__ __align__(16) char sK[2][16384];
  __shared__ __align__(16) char sV[2][16384];
  __shared__ __align__(16) char sP[4][2048];

  const int tid = threadIdx.x, lane = tid & 63, w = tid >> 6;
  const int cl = lane & 15, h4 = lane >> 4;
  // XCD-bijective swizzle: 512 blocks, 8 XCDs, 64 consecutive per XCD.
  const int swzb = (blockIdx.x & 7) * 64 + (blockIdx.x >> 3);
  const int s0 = (swzb & 127) * 16;
  const int hk = swzb >> 7;
  const int srow = s0 + cl;
  const int head = hk * Gn + w;
  const int swz = (cl & 7) << 4;

  const unsigned long long mymask = selm[(size_t)srow * HKn + hk];
  unsigned long long un = mymask;
  un |= __shfl_xor(un, 1); un |= __shfl_xor(un, 2);
  un |= __shfl_xor(un, 4); un |= __shfl_xor(un, 8);

  const int jmax = (s0 + 15) >> 6;
  const int jw0 = (s0 >= WINn - 1) ? (s0 - (WINn - 1)) >> 6 : 0;
  const unsigned long long allm = (2ull << jmax) - 1;

  const char* kh = (const char*)kbf + ((size_t)hk << 19);
  const char* vh = (const char*)vtb + ((size_t)hk << 19);

  bf16x8 qb[4];
#pragma unroll
  for (int ks = 0; ks < 4; ++ks)
    qb[ks] = *(const bf16x8*)((const char*)qbf +
        ((size_t)srow * HQn + head) * 256 + ks * 64 + h4 * 16);
  const float g0 = gates[((size_t)srow * HQn + head) * 3 + 0];
  const float g1 = gates[((size_t)srow * HQn + head) * 3 + 1];
  float* orow = out + ((size_t)srow * HQn + head) * Dn;

  for (int ph = 0; ph < 2; ++ph) {
    unsigned long long nm = ph ? (allm & ~((1ull << jw0) - 1)) : (un & allm);
    float m = -1e30f, den = 0.f;
    f32x4 O[8];
#pragma unroll
    for (int ef = 0; ef < 8; ++ef) { f32x4 z = {0.f,0.f,0.f,0.f}; O[ef] = z; }

    if (nm) {
      int j = (int)__builtin_ctzll(nm); nm &= nm - 1;
      stage_tile(kh, vh, j * 64, (char*)sK[0], (char*)sV[0], tid);
      __syncthreads();
      int cur = 0;
      while (true) {
        int jn = -1;
        if (nm) {
          jn = (int)__builtin_ctzll(nm); nm &= nm - 1;
          stage_tile(kh, vh, jn * 64, (char*)sK[cur ^ 1], (char*)sV[cur ^ 1], tid);
        }
        const int tb = j * 64;
        // ---- QK ----
        float xr[16];
#pragma unroll
        for (int mt = 0; mt < 4; ++mt) {
          f32x4 acc = {0.f, 0.f, 0.f, 0.f};
#pragma unroll
          for (int ks = 0; ks < 4; ++ks) {
            const int row = mt * 16 + cl;
            const bf16x8 ka = *(const bf16x8*)(sK[cur] + row * 256 +
                ((unsigned)(ks * 64 + h4 * 16) ^ swz));
            acc = mfma16(ka, qb[ks], acc);
          }
          xr[4*mt+0] = acc[0]; xr[4*mt+1] = acc[1];
          xr[4*mt+2] = acc[2]; xr[4*mt+3] = acc[3];
        }
        // ---- per-lane validity mask for this phase ----
        const bool selb = (mymask >> j) & 1ull;
        unsigned vm = 0u;
#pragma unroll
        for (int i = 0; i < 16; ++i) {
          const int token = tb + (i >> 2) * 16 + h4 * 4 + (i & 3);
          const bool cz = token <= srow;
          const bool ok = ph ? (cz && (srow - token) < WINn) : (cz && selb);
          if (ok) vm |= (1u << i);
        }
        // ---- online max (defer-max THR=8) ----
        float bm = -1e30f;
#pragma unroll
        for (int i = 0; i < 16; ++i) if ((vm >> i) & 1u) bm = fmaxf(bm, xr[i]);
        bm = fmaxf(bm, __shfl_xor(bm, 16));
        bm = fmaxf(bm, __shfl_xor(bm, 32));
        if (bm > m + 8.f) {
          const float sc = __expf(m - bm);
#pragma unroll
          for (int ef = 0; ef < 8; ++ef) O[ef] *= sc;
          den *= sc; m = bm;
        }
        // ---- exp in place; denominator ----
#pragma unroll
        for (int i = 0; i < 16; ++i) xr[i] = __expf(xr[i] - m);
#pragma unroll
        for (int i = 0; i < 16; ++i) den += ((vm >> i) & 1u) ? xr[i] : 0.f;
        // ---- P tile (masked values; all lanes always write) ----
#pragma unroll
        for (int mt = 0; mt < 4; ++mt) {
          const float p0 = ((vm >> (4*mt+0)) & 1u) ? xr[4*mt+0] : 0.f;
          const float p1 = ((vm >> (4*mt+1)) & 1u) ? xr[4*mt+1] : 0.f;
          const float p2 = ((vm >> (4*mt+2)) & 1u) ? xr[4*mt+2] : 0.f;
          const float p3 = ((vm >> (4*mt+3)) & 1u) ? xr[4*mt+3] : 0.f;
          uint2v u; u[0] = pk2(p0, p1); u[1] = pk2(p2, p3);
          *(uint2v*)(sP[w] + cl * 128 + ((unsigned)(mt * 32 + h4 * 8) ^ swz)) = u;
        }
        // ---- PV (unconditional) ----
#pragma unroll
        for (int kt = 0; kt < 2; ++kt) {
          const bf16x8 f = *(const bf16x8*)(sP[w] + cl * 128 +
              ((unsigned)(kt * 64 + h4 * 16) ^ swz));
#pragma unroll
          for (int ef = 0; ef < 8; ++ef) {
            const int vrow = ef * 16 + cl;
            const bf16x8 vf = *(const bf16x8*)(sV[cur] + vrow * 128 +
                ((unsigned)(kt * 64 + h4 * 16) ^ swz));
            O[ef] = mfma16(vf, f, O[ef]);
          }
        }
        __syncthreads();
        if (jn < 0) break;
        j = jn; cur ^= 1;
      }
    }
    // ---- phase epilogue: flush c*O into out, free the registers ----
    den += __shfl_xor(den, 16); den += __shfl_xor(den, 32);
    const float c = (ph ? g1 : g0) / fmaxf(den, 1e-20f);
#pragma unroll
    for (int ef = 0; ef < 8; ++ef) {
      float4* p = (float4*)(orow + ef * 16 + h4 * 4);
      float4 o = *p;
      o.x += c * O[ef][0];
      o.y += c * O[ef][1];
      o.z += c * O[ef][2];
      o.w += c * O[ef][3];
      *p = o;
    }
  }
}

// ---------------------------------------------------------------------------
extern "C" void kernel_launch(void* const* d_in, const int* in_sizes, int n_in,
                              void* d_out, int out_size, void* d_ws, size_t ws_size,
                              hipStream_t stream) {
  const float* q  = (const float*)d_in[0];
  const float* k  = (const float*)d_in[1];
  const float* v  = (const float*)d_in[2];
  const float* Wk = (const float*)d_in[3];
  const float* Wv = (const float*)d_in[4];
  const float* Wg = (const float*)d_in[5];
  const float* bg = (const float*)d_in[6];
  float* out = (float*)d_out;

  const int N = HKn * Cn * Dn;  // 65024
  float* part  = (float*)d_ws;                       // 8*N
  float* ck    = part + (size_t)8 * N;
  float* cv    = ck + N;
  float* gates = cv + N;                             // S*HQ*3 = 98304
  unsigned long long* selm = (unsigned long long*)(gates + (size_t)Sn * HQn * 3); // 8192
  unsigned short* qbf = (unsigned short*)(selm + (size_t)Sn * HKn);  // 4194304
  unsigned short* kbf = qbf + (size_t)Sn * HQn * Dn;                 // 1048576
  unsigned short* vtb = kbf + (size_t)Sn * HKn * Dn;                 // 1048576

  nsa_cvtq<<<2560, 256, 0, stream>>>(q, k, qbf, kbf);
  nsa_cvtv<<<dim3(32, HKn), 256, 0, stream>>>(v, vtb);
  nsa_compress<<<dim3(8, HKn, 8), 512, 0, stream>>>(k, v, Wk, Wv, part);
  nsa_reduce<<<dim3((N + 255) / 256), 256, 0, stream>>>(part, ck, cv);
  nsa_cmp_sel<<<dim3(Sn / 4, HKn), 256, 0, stream>>>(q, ck, cv, Wg, bg, gates, selm, out);
  nsa_attn<<<512, 256, 0, stream>>>(qbf, kbf, vtb, gates, selm, out);
}

// Round 7
// 321.223 us; speedup vs baseline: 14.9260x; 1.2278x over previous
//
#include <hip/hip_runtime.h>
#include <math.h>

#define HQn 16
#define HKn 4
#define Gn 4
#define Dn 128
#define STRIDEn 16
#define CBLKn 32
#define SBLKn 64
#define NSELn 16
#define WINn 512
#define Sn 2048
#define Cn 127
#define NBLKn 32

typedef float f32x4 __attribute__((ext_vector_type(4)));
typedef __bf16 bf16x8 __attribute__((ext_vector_type(8)));
typedef unsigned short ushort8 __attribute__((ext_vector_type(8)));
typedef unsigned int uint2v __attribute__((ext_vector_type(2)));

__device__ inline f32x4 mfma16(bf16x8 a, bf16x8 b, f32x4 c) {
  return __builtin_amdgcn_mfma_f32_16x16x32_bf16(a, b, c, 0, 0, 0);
}
__device__ inline unsigned short f2bfu(float x) {
  return __builtin_bit_cast(unsigned short, (__bf16)x);
}
__device__ inline unsigned pk2(float a, float b) {
  return (unsigned)f2bfu(a) | ((unsigned)f2bfu(b) << 16);
}
__device__ inline void gll16(const void* g, void* l) {
  __builtin_amdgcn_global_load_lds(
      (const __attribute__((address_space(1))) unsigned*)g,
      (__attribute__((address_space(3))) unsigned*)l, 16, 0, 0);
}

// ---------------------------------------------------------------------------
// Convert q (pre-scaled) and k to bf16; k relayout [t][hk][d] -> [hk][t][d].
// ---------------------------------------------------------------------------
__global__ __launch_bounds__(256)
void nsa_cvtq(const float* __restrict__ q, const float* __restrict__ k,
              unsigned short* __restrict__ qbf, unsigned short* __restrict__ kbf) {
  const float scale = 0.08838834764831845f;
  const int gid = blockIdx.x * 256 + threadIdx.x;
  if (gid < 524288) {
    const size_t i = (size_t)gid * 8;
    const float4* s = (const float4*)(q + i);
    float4 a = s[0], b = s[1];
    ushort8 u;
    u[0]=f2bfu(a.x*scale); u[1]=f2bfu(a.y*scale); u[2]=f2bfu(a.z*scale); u[3]=f2bfu(a.w*scale);
    u[4]=f2bfu(b.x*scale); u[5]=f2bfu(b.y*scale); u[6]=f2bfu(b.z*scale); u[7]=f2bfu(b.w*scale);
    *(ushort8*)(qbf + i) = u;
  } else {
    const int g2 = gid - 524288;           // < 131072
    const size_t o = (size_t)g2 * 8;
    const int hk = (int)(o >> 18);
    const int r  = (int)(o & 262143);
    const int t = r >> 7, d = r & 127;
    const float4* s = (const float4*)(k + ((size_t)t * 4 + hk) * 128 + d);
    float4 a = s[0], b = s[1];
    ushort8 u;
    u[0]=f2bfu(a.x); u[1]=f2bfu(a.y); u[2]=f2bfu(a.z); u[3]=f2bfu(a.w);
    u[4]=f2bfu(b.x); u[5]=f2bfu(b.y); u[6]=f2bfu(b.z); u[7]=f2bfu(b.w);
    *(ushort8*)(kbf + o) = u;
  }
}

// ---------------------------------------------------------------------------
// V -> bf16 transposed: vtb[hk][d][t]
// ---------------------------------------------------------------------------
__global__ __launch_bounds__(256)
void nsa_cvtv(const float* __restrict__ v, unsigned short* __restrict__ vtb) {
  __shared__ __align__(16) unsigned short tile[64][136];
  const int tid = threadIdx.x;
  const int tb = blockIdx.x * 64, hk = blockIdx.y;
  {
    const int tl = tid >> 2, dc = (tid & 3) * 32;
    const float4* src = (const float4*)(v + ((size_t)(tb + tl) * 4 + hk) * 128 + dc);
#pragma unroll
    for (int ii = 0; ii < 4; ++ii) {
      float4 a = src[ii * 2], b = src[ii * 2 + 1];
      ushort8 u;
      u[0]=f2bfu(a.x); u[1]=f2bfu(a.y); u[2]=f2bfu(a.z); u[3]=f2bfu(a.w);
      u[4]=f2bfu(b.x); u[5]=f2bfu(b.y); u[6]=f2bfu(b.z); u[7]=f2bfu(b.w);
      *(ushort8*)&tile[tl][dc + ii * 8] = u;
    }
  }
  __syncthreads();
  {
    const int d = tid >> 1, th = tid & 1;
    ushort8 u[4];
#pragma unroll
    for (int ii = 0; ii < 4; ++ii)
#pragma unroll
      for (int t = 0; t < 8; ++t)
        u[ii][t] = tile[th * 32 + ii * 8 + t][d];
    ushort8* dst = (ushort8*)(vtb + (size_t)hk * 262144 + (size_t)d * 2048 + tb + th * 32);
#pragma unroll
    for (int ii = 0; ii < 4; ++ii) dst[ii] = u[ii];
  }
}

// ---------------------------------------------------------------------------
// Compression partials (f32, bit-identical expression/order to verified r2).
// ---------------------------------------------------------------------------
__global__ __launch_bounds__(512)
void nsa_compress(const float* __restrict__ k, const float* __restrict__ v,
                  const float* __restrict__ Wk, const float* __restrict__ Wv,
                  float* __restrict__ part) {
  const int wf = blockIdx.z;
  const int which = wf >> 2, fs = wf & 3;
  const int hk = blockIdx.y;
  const int c = blockIdx.x * 16 + (threadIdx.x >> 5);
  const int e0 = (threadIdx.x & 31) * 4;
  if (c >= Cn) return;
  const float* src = which ? v : k;
  const float* W = which ? Wv : Wk;
  float a0 = 0.f, a1 = 0.f, a2 = 0.f, a3 = 0.f;
  const int w0 = fs * 8;
  for (int wi = 0; wi < 8; ++wi) {
    const int row = c * STRIDEn + w0 + wi;
    const float4* kr = (const float4*)(src + ((size_t)row * HKn + hk) * Dn);
    const float* Wr = W + (size_t)(w0 + wi) * Dn * Dn;
#pragma unroll 4
    for (int d4 = 0; d4 < 32; ++d4) {
      float4 kk = kr[d4];
      float4 w0v = *(const float4*)(Wr + (size_t)(d4 * 4 + 0) * Dn + e0);
      float4 w1v = *(const float4*)(Wr + (size_t)(d4 * 4 + 1) * Dn + e0);
      float4 w2v = *(const float4*)(Wr + (size_t)(d4 * 4 + 2) * Dn + e0);
      float4 w3v = *(const float4*)(Wr + (size_t)(d4 * 4 + 3) * Dn + e0);
      a0 += kk.x * w0v.x + kk.y * w1v.x + kk.z * w2v.x + kk.w * w3v.x;
      a1 += kk.x * w0v.y + kk.y * w1v.y + kk.z * w2v.y + kk.w * w3v.y;
      a2 += kk.x * w0v.z + kk.y * w1v.z + kk.z * w2v.z + kk.w * w3v.z;
      a3 += kk.x * w0v.w + kk.y * w1v.w + kk.z * w2v.w + kk.w * w3v.w;
    }
  }
  float* d = part + (size_t)(which * 4 + fs) * (HKn * Cn * Dn)
                  + ((size_t)hk * Cn + c) * Dn + e0;
  d[0] = a0; d[1] = a1; d[2] = a2; d[3] = a3;
}

// Reduce partials; also emit transposed ckt[hk][d][128(c)] for coalesced
// logits reads in cmp_sel (bitwise same values, layout only).
__global__ void nsa_reduce(const float* __restrict__ part,
                           float* __restrict__ ck, float* __restrict__ cv,
                           float* __restrict__ ckt) {
  const int i = blockIdx.x * 256 + threadIdx.x;
  const int N = HKn * Cn * Dn;
  if (i < N) {
    const float kv = ((part[i] + part[(size_t)N + i]) + (part[2 * (size_t)N + i] + part[3 * (size_t)N + i]));
    ck[i] = kv;
    cv[i] = ((part[4 * (size_t)N + i] + part[5 * (size_t)N + i]) + (part[6 * (size_t)N + i] + part[7 * (size_t)N + i]));
    const int hk = i / (Cn * Dn);
    const int r  = i - hk * (Cn * Dn);
    const int c  = r >> 7, d = r & 127;
    ckt[((size_t)hk * Dn + d) * 128 + c] = kv;
  }
}

// ---------------------------------------------------------------------------
// Compressed attention + selection + gates. Selection math bit-identical.
// Logits read transposed ckt (coalesced); rank-based exact top-16 (no serial
// shfl chain); q staged in LDS; second c-half skipped when cmax<=64.
// ---------------------------------------------------------------------------
__global__ __launch_bounds__(256)
void nsa_cmp_sel(const float* __restrict__ q, const float* __restrict__ ckt,
                 const float* __restrict__ cv, const float* __restrict__ Wg,
                 const float* __restrict__ bg, float* __restrict__ gates,
                 unsigned long long* __restrict__ selm, float* __restrict__ out) {
  __shared__ float pcs2[4][128][4];
  __shared__ float score_l[4][128];
  __shared__ float gate2_l[4][Gn];
  __shared__ float pool_l[4][32];
  __shared__ __align__(16) float qs_l[4][Gn][Dn];
  const int wid = threadIdx.x >> 6, lane = threadIdx.x & 63;
  const int s = blockIdx.x * 4 + wid;
  const int hk = blockIdx.y;
  const float scale = 0.08838834764831845f;
  const int cmax = (s >= CBLKn - 1) ? ((s - (CBLKn - 1)) >> 4) + 1 : 0;

  // stage q rows for this wave (broadcast reads later)
  {
    const float4* qg = (const float4*)(q + ((size_t)s * HQn + hk * Gn) * Dn);
    float4* dst = (float4*)&qs_l[wid][0][0];
    dst[lane] = qg[lane];
    dst[lane + 64] = qg[lane + 64];
  }

  // ---- compressed logits from transposed ckt (coalesced, lane = c) ----
  const float* ckt_h = ckt + (size_t)hk * Dn * 128;
  const int c1l = (lane + 64 < Cn) ? lane + 64 : Cn - 1;
  float a00=0,a10=0,a20=0,a30=0;
#pragma unroll 8
  for (int d4 = 0; d4 < 32; ++d4) {
    const float kx = ckt_h[(d4 * 4 + 0) * 128 + lane];
    const float ky = ckt_h[(d4 * 4 + 1) * 128 + lane];
    const float kz = ckt_h[(d4 * 4 + 2) * 128 + lane];
    const float kw = ckt_h[(d4 * 4 + 3) * 128 + lane];
    const float4 q0 = *(const float4*)&qs_l[wid][0][d4 * 4];
    const float4 q1 = *(const float4*)&qs_l[wid][1][d4 * 4];
    const float4 q2 = *(const float4*)&qs_l[wid][2][d4 * 4];
    const float4 q3 = *(const float4*)&qs_l[wid][3][d4 * 4];
    a00 += kx*q0.x + ky*q0.y + kz*q0.z + kw*q0.w;
    a10 += kx*q1.x + ky*q1.y + kz*q1.z + kw*q1.w;
    a20 += kx*q2.x + ky*q2.y + kz*q2.z + kw*q2.w;
    a30 += kx*q3.x + ky*q3.y + kz*q3.z + kw*q3.w;
  }
  float x0[4] = {a00*scale, a10*scale, a20*scale, a30*scale};
  float x1[4] = {-1e30f, -1e30f, -1e30f, -1e30f};
  if (cmax > 64) {
    float a01=0,a11=0,a21=0,a31=0;
#pragma unroll 8
    for (int d4 = 0; d4 < 32; ++d4) {
      const float kx = ckt_h[(d4 * 4 + 0) * 128 + c1l];
      const float ky = ckt_h[(d4 * 4 + 1) * 128 + c1l];
      const float kz = ckt_h[(d4 * 4 + 2) * 128 + c1l];
      const float kw = ckt_h[(d4 * 4 + 3) * 128 + c1l];
      const float4 q0 = *(const float4*)&qs_l[wid][0][d4 * 4];
      const float4 q1 = *(const float4*)&qs_l[wid][1][d4 * 4];
      const float4 q2 = *(const float4*)&qs_l[wid][2][d4 * 4];
      const float4 q3 = *(const float4*)&qs_l[wid][3][d4 * 4];
      a01 += kx*q0.x + ky*q0.y + kz*q0.z + kw*q0.w;
      a11 += kx*q1.x + ky*q1.y + kz*q1.z + kw*q1.w;
      a21 += kx*q2.x + ky*q2.y + kz*q2.z + kw*q2.w;
      a31 += kx*q3.x + ky*q3.y + kz*q3.z + kw*q3.w;
    }
    x1[0]=a01*scale; x1[1]=a11*scale; x1[2]=a21*scale; x1[3]=a31*scale;
  }

  // ---- masked softmax per g over c (bit-identical) ----
  float p0[4], p1[4];
#pragma unroll
  for (int g = 0; g < 4; ++g) {
    float m = -1e30f;
    if (lane < cmax) m = x0[g];
    if (lane + 64 < cmax) m = fmaxf(m, x1[g]);
    for (int off = 32; off; off >>= 1) m = fmaxf(m, __shfl_xor(m, off));
    float e0v = (lane < cmax) ? __expf(x0[g] - m) : 0.f;
    float e1v = (lane + 64 < cmax) ? __expf(x1[g] - m) : 0.f;
    float sum = e0v + e1v;
    for (int off = 32; off; off >>= 1) sum += __shfl_xor(sum, off);
    float inv = 1.f / fmaxf(sum, 1e-20f);
    p0[g] = e0v * inv; p1[g] = e1v * inv;
  }
  {
    float4 v0 = {p0[0], p0[1], p0[2], p0[3]};
    float4 v1 = {p1[0], p1[1], p1[2], p1[3]};
    *(float4*)&pcs2[wid][lane][0] = v0;
    *(float4*)&pcs2[wid][lane + 64][0] = v1;
    score_l[wid][lane] = v0.x + v0.y + v0.z + v0.w;
    score_l[wid][lane + 64] = v1.x + v1.y + v1.z + v1.w;
  }

  // ---- AvgPool(5,4,ceil) + rank-based exact stable top-16 ----
  float pooled = -INFINITY;
  if (lane < NBLKn) {
    float sum = 0.f; int cnt = 0;
    for (int kp = 0; kp <= 4; ++kp) {
      int idx = lane * 4 + kp;
      if (idx < Cn) { sum += score_l[wid][idx]; cnt++; }
    }
    pooled = sum / (float)cnt;
    pool_l[wid][lane] = pooled;
  }
  int rank = 0;
  if (lane < NBLKn) {
#pragma unroll
    for (int i = 0; i < NBLKn; ++i) {
      const float vi = pool_l[wid][i];
      rank += (vi > pooled || (vi == pooled && i < lane)) ? 1 : 0;
    }
  }
  const unsigned long long msk = __ballot(lane < NBLKn && rank < NSELn);
  if (lane == 0) selm[(size_t)s * HKn + hk] = msk;

  // ---- gates (q from LDS) ----
  if (lane < 48) {
    const int gj = lane >> 2, ch = lane & 3;
    const int g = gj / 3, jj = gj % 3;
    float a = 0.f;
#pragma unroll 8
    for (int d = ch * 32; d < ch * 32 + 32; ++d) a += qs_l[wid][g][d] * Wg[d * 3 + jj];
    a += __shfl_xor(a, 1); a += __shfl_xor(a, 2);
    if (ch == 0) {
      const float gv = 1.f / (1.f + __expf(-(a + bg[jj])));
      gates[((size_t)s * HQn + hk * Gn + g) * 3 + jj] = gv;
      if (jj == 2) gate2_l[wid][g] = gv;
    }
  }

  // ---- compressed PV, 2-way unrolled, pre-gated into out ----
  {
    float b0[4] = {0,0,0,0}, b1[4] = {0,0,0,0};
    float c0a[4] = {0,0,0,0}, c1a[4] = {0,0,0,0};
    int cc = 0;
    for (; cc + 2 <= cmax; cc += 2) {
      float4 pp = *(const float4*)&pcs2[wid][cc][0];
      float4 qq = *(const float4*)&pcs2[wid][cc + 1][0];
      float va1 = cv[((size_t)hk * Cn + cc) * Dn + lane];
      float va2 = cv[((size_t)hk * Cn + cc) * Dn + lane + 64];
      float vb1 = cv[((size_t)hk * Cn + cc + 1) * Dn + lane];
      float vb2 = cv[((size_t)hk * Cn + cc + 1) * Dn + lane + 64];
      b0[0] += pp.x*va1; b0[1] += pp.y*va1; b0[2] += pp.z*va1; b0[3] += pp.w*va1;
      b1[0] += pp.x*va2; b1[1] += pp.y*va2; b1[2] += pp.z*va2; b1[3] += pp.w*va2;
      c0a[0] += qq.x*vb1; c0a[1] += qq.y*vb1; c0a[2] += qq.z*vb1; c0a[3] += qq.w*vb1;
      c1a[0] += qq.x*vb2; c1a[1] += qq.y*vb2; c1a[2] += qq.z*vb2; c1a[3] += qq.w*vb2;
    }
    if (cc < cmax) {
      float4 pp = *(const float4*)&pcs2[wid][cc][0];
      float va1 = cv[((size_t)hk * Cn + cc) * Dn + lane];
      float va2 = cv[((size_t)hk * Cn + cc) * Dn + lane + 64];
      b0[0] += pp.x*va1; b0[1] += pp.y*va1; b0[2] += pp.z*va1; b0[3] += pp.w*va1;
      b1[0] += pp.x*va2; b1[1] += pp.y*va2; b1[2] += pp.z*va2; b1[3] += pp.w*va2;
    }
#pragma unroll
    for (int g = 0; g < 4; ++g) {
      float g2 = gate2_l[wid][g];
      out[((size_t)s * HQn + hk * Gn + g) * Dn + lane] = g2 * (b0[g] + c0a[g]);
      out[((size_t)s * HQn + hk * Gn + g) * Dn + lane + 64] = g2 * (b1[g] + c1a[g]);
    }
  }
}

// ---------------------------------------------------------------------------
// Stage one 64-token K tile + V^T tile via global_load_lds (linear LDS dest,
// inverse-swizzled global source; read side applies the same XOR).
// ---------------------------------------------------------------------------
__device__ inline void stage_tile(const char* kh, const char* vh, int tb,
                                  char* kb, char* vb, int tid) {
#pragma unroll
  for (int i = 0; i < 4; ++i) {
    const int L = i * 4096 + tid * 16;
    const int row = L >> 8, colb = L & 255;
    gll16(kh + ((size_t)(tb + row) << 8) + (colb ^ ((row & 7) << 4)), kb + L);
  }
#pragma unroll
  for (int i = 0; i < 4; ++i) {
    const int L = i * 4096 + tid * 16;
    const int e = L >> 7, colb = L & 127;
    gll16(vh + ((size_t)e << 12) + ((size_t)tb << 1) + (colb ^ ((e & 7) << 4)), vb + L);
  }
}

// ---------------------------------------------------------------------------
// Two-phase online-softmax attention (phase 0 = selected, phase 1 = window).
// Single accumulator O[8] per phase, flushed to out after each phase.
// ---------------------------------------------------------------------------
__global__ __launch_bounds__(256, 2)
void nsa_attn(const unsigned short* __restrict__ qbf,
              const unsigned short* __restrict__ kbf,
              const unsigned short* __restrict__ vtb,
              const float* __restrict__ gates,
              const unsigned long long* __restrict__ selm,
              float* __restrict__ out) {
  __shared__ __align__(16) char sK[2][16384];
  __shared__ __align__(16) char sV[2][16384];
  __shared__ __align__(16) char sP[4][2048];

  const int tid = threadIdx.x, lane = tid & 63, w = tid >> 6;
  const int cl = lane & 15, h4 = lane >> 4;
  const int swzb = (blockIdx.x & 7) * 64 + (blockIdx.x >> 3);
  const int s0 = (swzb & 127) * 16;
  const int hk = swzb >> 7;
  const int srow = s0 + cl;
  const int head = hk * Gn + w;
  const int swz = (cl & 7) << 4;

  const unsigned long long mymask = selm[(size_t)srow * HKn + hk];
  unsigned long long un = mymask;
  un |= __shfl_xor(un, 1); un |= __shfl_xor(un, 2);
  un |= __shfl_xor(un, 4); un |= __shfl_xor(un, 8);

  const int jmax = (s0 + 15) >> 6;
  const int jw0 = (s0 >= WINn - 1) ? (s0 - (WINn - 1)) >> 6 : 0;
  const unsigned long long allm = (2ull << jmax) - 1;

  const char* kh = (const char*)kbf + ((size_t)hk << 19);
  const char* vh = (const char*)vtb + ((size_t)hk << 19);

  bf16x8 qb[4];
#pragma unroll
  for (int ks = 0; ks < 4; ++ks)
    qb[ks] = *(const bf16x8*)((const char*)qbf +
        ((size_t)srow * HQn + head) * 256 + ks * 64 + h4 * 16);
  const float g0 = gates[((size_t)srow * HQn + head) * 3 + 0];
  const float g1 = gates[((size_t)srow * HQn + head) * 3 + 1];
  float* orow = out + ((size_t)srow * HQn + head) * Dn;

  for (int ph = 0; ph < 2; ++ph) {
    unsigned long long nm = ph ? (allm & ~((1ull << jw0) - 1)) : (un & allm);
    float m = -1e30f, den = 0.f;
    f32x4 O[8];
#pragma unroll
    for (int ef = 0; ef < 8; ++ef) { f32x4 z = {0.f,0.f,0.f,0.f}; O[ef] = z; }

    if (nm) {
      int j = (int)__builtin_ctzll(nm); nm &= nm - 1;
      stage_tile(kh, vh, j * 64, (char*)sK[0], (char*)sV[0], tid);
      __syncthreads();
      int cur = 0;
      while (true) {
        int jn = -1;
        if (nm) {
          jn = (int)__builtin_ctzll(nm); nm &= nm - 1;
          stage_tile(kh, vh, jn * 64, (char*)sK[cur ^ 1], (char*)sV[cur ^ 1], tid);
        }
        const int tb = j * 64;
        float xr[16];
#pragma unroll
        for (int mt = 0; mt < 4; ++mt) {
          f32x4 acc = {0.f, 0.f, 0.f, 0.f};
#pragma unroll
          for (int ks = 0; ks < 4; ++ks) {
            const int row = mt * 16 + cl;
            const bf16x8 ka = *(const bf16x8*)(sK[cur] + row * 256 +
                ((unsigned)(ks * 64 + h4 * 16) ^ swz));
            acc = mfma16(ka, qb[ks], acc);
          }
          xr[4*mt+0] = acc[0]; xr[4*mt+1] = acc[1];
          xr[4*mt+2] = acc[2]; xr[4*mt+3] = acc[3];
        }
        const bool selb = (mymask >> j) & 1ull;
        unsigned vm = 0u;
#pragma unroll
        for (int i = 0; i < 16; ++i) {
          const int token = tb + (i >> 2) * 16 + h4 * 4 + (i & 3);
          const bool cz = token <= srow;
          const bool ok = ph ? (cz && (srow - token) < WINn) : (cz && selb);
          if (ok) vm |= (1u << i);
        }
        float bm = -1e30f;
#pragma unroll
        for (int i = 0; i < 16; ++i) if ((vm >> i) & 1u) bm = fmaxf(bm, xr[i]);
        bm = fmaxf(bm, __shfl_xor(bm, 16));
        bm = fmaxf(bm, __shfl_xor(bm, 32));
        if (bm > m + 8.f) {
          const float sc = __expf(m - bm);
#pragma unroll
          for (int ef = 0; ef < 8; ++ef) O[ef] *= sc;
          den *= sc; m = bm;
        }
#pragma unroll
        for (int i = 0; i < 16; ++i) xr[i] = __expf(xr[i] - m);
#pragma unroll
        for (int i = 0; i < 16; ++i) den += ((vm >> i) & 1u) ? xr[i] : 0.f;
#pragma unroll
        for (int mt = 0; mt < 4; ++mt) {
          const float p0 = ((vm >> (4*mt+0)) & 1u) ? xr[4*mt+0] : 0.f;
          const float p1 = ((vm >> (4*mt+1)) & 1u) ? xr[4*mt+1] : 0.f;
          const float p2 = ((vm >> (4*mt+2)) & 1u) ? xr[4*mt+2] : 0.f;
          const float p3 = ((vm >> (4*mt+3)) & 1u) ? xr[4*mt+3] : 0.f;
          uint2v u; u[0] = pk2(p0, p1); u[1] = pk2(p2, p3);
          *(uint2v*)(sP[w] + cl * 128 + ((unsigned)(mt * 32 + h4 * 8) ^ swz)) = u;
        }
#pragma unroll
        for (int kt = 0; kt < 2; ++kt) {
          const bf16x8 f = *(const bf16x8*)(sP[w] + cl * 128 +
              ((unsigned)(kt * 64 + h4 * 16) ^ swz));
#pragma unroll
          for (int ef = 0; ef < 8; ++ef) {
            const int vrow = ef * 16 + cl;
            const bf16x8 vf = *(const bf16x8*)(sV[cur] + vrow * 128 +
                ((unsigned)(kt * 64 + h4 * 16) ^ swz));
            O[ef] = mfma16(vf, f, O[ef]);
          }
        }
        __syncthreads();
        if (jn < 0) break;
        j = jn; cur ^= 1;
      }
    }
    den += __shfl_xor(den, 16); den += __shfl_xor(den, 32);
    const float c = (ph ? g1 : g0) / fmaxf(den, 1e-20f);
#pragma unroll
    for (int ef = 0; ef < 8; ++ef) {
      float4* p = (float4*)(orow + ef * 16 + h4 * 4);
      float4 o = *p;
      o.x += c * O[ef][0];
      o.y += c * O[ef][1];
      o.z += c * O[ef][2];
      o.w += c * O[ef][3];
      *p = o;
    }
  }
}

// ---------------------------------------------------------------------------
extern "C" void kernel_launch(void* const* d_in, const int* in_sizes, int n_in,
                              void* d_out, int out_size, void* d_ws, size_t ws_size,
                              hipStream_t stream) {
  const float* q  = (const float*)d_in[0];
  const float* k  = (const float*)d_in[1];
  const float* v  = (const float*)d_in[2];
  const float* Wk = (const float*)d_in[3];
  const float* Wv = (const float*)d_in[4];
  const float* Wg = (const float*)d_in[5];
  const float* bg = (const float*)d_in[6];
  float* out = (float*)d_out;

  const int N = HKn * Cn * Dn;  // 65024
  float* part  = (float*)d_ws;                       // 8*N
  float* ck    = part + (size_t)8 * N;
  float* cv    = ck + N;
  float* gates = cv + N;                             // S*HQ*3 = 98304
  unsigned long long* selm = (unsigned long long*)(gates + (size_t)Sn * HQn * 3); // 8192
  unsigned short* qbf = (unsigned short*)(selm + (size_t)Sn * HKn);  // 4194304
  unsigned short* kbf = qbf + (size_t)Sn * HQn * Dn;                 // 1048576
  unsigned short* vtb = kbf + (size_t)Sn * HKn * Dn;                 // 1048576
  float* ckt = (float*)(vtb + (size_t)Sn * HKn * Dn);                // 4*128*128

  nsa_cvtq<<<2560, 256, 0, stream>>>(q, k, qbf, kbf);
  nsa_cvtv<<<dim3(32, HKn), 256, 0, stream>>>(v, vtb);
  nsa_compress<<<dim3(8, HKn, 8), 512, 0, stream>>>(k, v, Wk, Wv, part);
  nsa_reduce<<<dim3((N + 255) / 256), 256, 0, stream>>>(part, ck, cv, ckt);
  nsa_cmp_sel<<<dim3(Sn / 4, HKn), 256, 0, stream>>>(q, ckt, cv, Wg, bg, gates, selm, out);
  nsa_attn<<<512, 256, 0, stream>>>(qbf, kbf, vtb, gates, selm, out);
}